// Round 3
// baseline (5272.450 us; speedup 1.0000x reference)
//
#include <hip/hip_runtime.h>
#include <math.h>

// MambaBlock: B=8, T=2048, D_MODEL=1024, D_STATE=256, all fp32.
//
// ws layout (176 MB):
//   u   = x @ W_in + b_in                       [16384,256]   ws +   0 MB
//   u2  = u @ Bm                                [16384,256]   ws +  16 MB
//   h   = scan(tanh(h@A + u2_t))                [16384,256]   ws +  32 MB
//   big = u @ D^T  (+= h @ C^T later)           [16384,1024]  ws +  48 MB
//   g   = sigmoid(x @ W_gate + b_gate)          [16384,1024]  ws + 112 MB
//   out = (g*big+(1-g)*x) @ W_out + b_out + x   d_out

enum { E_NONE = 0, E_BIAS = 1, E_SIG = 2, E_ACC = 3, E_BIASRES = 4 };

// ---------------- fp32 tile GEMM (unchanged) ----------------
template <int EPI, bool BT>
__global__ __launch_bounds__(256) void gemm64(
    const float* __restrict__ Ag, const float* __restrict__ Bg,
    const float* __restrict__ bias, const float* __restrict__ res,
    float* Cg, int M, int N, int K)
{
    __shared__ float As[16][68];
    __shared__ float Bs[16][68];
    const int tid = threadIdx.x;
    const int m0 = blockIdx.y * 64, n0 = blockIdx.x * 64;
    const int tm = (tid >> 4) << 2;
    const int tn = (tid & 15) << 2;
    const int arow = tid >> 2;
    const int acol = (tid & 3) << 2;
    const int brow = tid >> 4;
    const int bcol = (tid & 15) << 2;
    float acc[4][4] = {};

    for (int k0 = 0; k0 < K; k0 += 16) {
        float4 a4 = *(const float4*)(Ag + (size_t)(m0 + arow) * K + k0 + acol);
        As[acol + 0][arow] = a4.x; As[acol + 1][arow] = a4.y;
        As[acol + 2][arow] = a4.z; As[acol + 3][arow] = a4.w;
        if (!BT) {
            float4 b4 = *(const float4*)(Bg + (size_t)(k0 + brow) * N + n0 + bcol);
            Bs[brow][bcol + 0] = b4.x; Bs[brow][bcol + 1] = b4.y;
            Bs[brow][bcol + 2] = b4.z; Bs[brow][bcol + 3] = b4.w;
        } else {
            float4 b4 = *(const float4*)(Bg + (size_t)(n0 + arow) * K + k0 + acol);
            Bs[acol + 0][arow] = b4.x; Bs[acol + 1][arow] = b4.y;
            Bs[acol + 2][arow] = b4.z; Bs[acol + 3][arow] = b4.w;
        }
        __syncthreads();
#pragma unroll
        for (int k = 0; k < 16; ++k) {
            float am[4], bv[4];
#pragma unroll
            for (int i = 0; i < 4; ++i) am[i] = As[k][tm + i];
#pragma unroll
            for (int j = 0; j < 4; ++j) bv[j] = Bs[k][tn + j];
#pragma unroll
            for (int i = 0; i < 4; ++i)
#pragma unroll
                for (int j = 0; j < 4; ++j)
                    acc[i][j] = fmaf(am[i], bv[j], acc[i][j]);
        }
        __syncthreads();
    }

#pragma unroll
    for (int i = 0; i < 4; ++i) {
        const int m = m0 + tm + i, n = n0 + tn;
        const size_t idx = (size_t)m * N + n;
        float4 v = make_float4(acc[i][0], acc[i][1], acc[i][2], acc[i][3]);
        if (EPI == E_BIAS || EPI == E_SIG || EPI == E_BIASRES) {
            v.x += bias[n + 0]; v.y += bias[n + 1];
            v.z += bias[n + 2]; v.w += bias[n + 3];
        }
        if (EPI == E_SIG) {
            v.x = 1.f / (1.f + expf(-v.x)); v.y = 1.f / (1.f + expf(-v.y));
            v.z = 1.f / (1.f + expf(-v.z)); v.w = 1.f / (1.f + expf(-v.w));
        }
        if (EPI == E_ACC) {
            float4 c = *(const float4*)(Cg + idx);
            v.x += c.x; v.y += c.y; v.z += c.z; v.w += c.w;
        }
        if (EPI == E_BIASRES) {
            float4 r = *(const float4*)(res + idx);
            v.x += r.x; v.y += r.y; v.z += r.z; v.w += r.w;
        }
        *(float4*)(Cg + idx) = v;
    }
}

// ---------------- MFMA scan ----------------
// One block, 4 waves, all 8 batches. Per step: Y^T = A^T @ H^T via
// mfma_f32_16x16x32_bf16 (M=state 256, N=batch 8 pad 16, K=state 256).
// A^T fragments in registers (128 VGPR/lane, loaded once). H in LDS as
// bf16, [32 kgroups][16 batches][8 bf16], kg stride 288 B. Double-buffered.
// KEY vs R2: raw s_barrier + manual lgkmcnt(0) only — global h-stores and
// u2 prefetch loads stay in the vmcnt queue ACROSS steps (never drained at
// the barrier). u2 pipelined 2 steps ahead in ping-pong registers.
typedef __attribute__((ext_vector_type(8))) short bf16x8;
typedef __attribute__((ext_vector_type(4))) float f32x4;

static __device__ inline unsigned short f2bf(float f) {
    unsigned u = __builtin_bit_cast(unsigned, f);
    unsigned r = (u + 0x7fff + ((u >> 16) & 1)) >> 16;
    return (unsigned short)r;
}
static __device__ inline unsigned pack2(float a, float b) {
    return (unsigned)f2bf(a) | ((unsigned)f2bf(b) << 16);
}
static __device__ inline float tanh_fast(float x) {
    float e = __builtin_amdgcn_exp2f(x * 2.8853900817779268f);
    float t = __builtin_amdgcn_rcpf(e + 1.0f);
    return fmaf(-2.0f, t, 1.0f);
}

__global__ __launch_bounds__(256, 1) void scan_mfma(
    const float* __restrict__ Amat, const float* __restrict__ u2,
    float* __restrict__ hout)
{
    constexpr int T = 2048;
    constexpr int KGSTRIDE = 288;
    __shared__ unsigned char Hlds[2][32 * KGSTRIDE];

    const int tid = threadIdx.x;
    const int w = tid >> 6;
    const int l = tid & 63;
    const int r = l & 15;          // batch (0..7 real)
    const int g = l >> 4;          // k-subgroup / C row-group
    const bool act = (r < 8);

    for (int i = tid; i < 2 * 32 * KGSTRIDE / 4; i += 256)
        ((unsigned*)Hlds)[i] = 0u;

    // A^T fragments: lane holds A^T[m][k] = Amat[k][m], m = w*64+mti*16+r,
    // k = kt*32 + g*8 + j.
    bf16x8 af[4][8];
#pragma unroll
    for (int mti = 0; mti < 4; ++mti) {
        const int m = w * 64 + mti * 16 + r;
#pragma unroll
        for (int kt = 0; kt < 8; ++kt) {
            unsigned wds[4];
#pragma unroll
            for (int jw = 0; jw < 4; ++jw) {
                const int k = kt * 32 + g * 8 + jw * 2;
                wds[jw] = pack2(Amat[(size_t)k * 256 + m],
                                Amat[(size_t)(k + 1) * 256 + m]);
            }
            af[mti][kt] = __builtin_bit_cast(bf16x8, *(uint4*)wds);
        }
    }

    const float* u2p[4];
    float* hp[4];
#pragma unroll
    for (int mti = 0; mti < 4; ++mti) {
        const size_t base = ((size_t)r * T) * 256 + (w * 64 + mti * 16 + g * 4);
        u2p[mti] = u2 + base;
        hp[mti]  = hout + base;
    }

    f32x4 cur0[4], cur1[4];
    if (act) {
#pragma unroll
        for (int mti = 0; mti < 4; ++mti) {
            cur0[mti] = *(const f32x4*)(u2p[mti]);                  // t=0
            cur1[mti] = *(const f32x4*)(u2p[mti] + 256);            // t=1
        }
    }
    __syncthreads();

#define SCAN_ONESTEP(BUF, CURX, tcur)                                         \
  {                                                                           \
    bf16x8 hf[8];                                                             \
    _Pragma("unroll")                                                         \
    for (int kt = 0; kt < 8; ++kt)                                            \
      hf[kt] = *(const bf16x8*)(&Hlds[BUF][(kt * 4 + g) * KGSTRIDE + r * 16]);\
    _Pragma("unroll")                                                         \
    for (int mti = 0; mti < 4; ++mti) {                                       \
      f32x4 pa = {0.f, 0.f, 0.f, 0.f}, pb = {0.f, 0.f, 0.f, 0.f};             \
      _Pragma("unroll")                                                       \
      for (int kt = 0; kt < 4; ++kt) {                                        \
        pa = __builtin_amdgcn_mfma_f32_16x16x32_bf16(af[mti][kt], hf[kt],     \
                                                     pa, 0, 0, 0);            \
        pb = __builtin_amdgcn_mfma_f32_16x16x32_bf16(af[mti][kt + 4],         \
                                                     hf[kt + 4], pb, 0, 0, 0);\
      }                                                                       \
      if (act) {                                                              \
        f32x4 s, hv;                                                          \
        _Pragma("unroll")                                                     \
        for (int q = 0; q < 4; ++q) s[q] = pa[q] + pb[q] + CURX[mti][q];      \
        if ((tcur) + 2 < T)                                                   \
          CURX[mti] = *(const f32x4*)(u2p[mti] + (size_t)((tcur) + 2) * 256); \
        _Pragma("unroll")                                                     \
        for (int q = 0; q < 4; ++q) hv[q] = tanh_fast(s[q]);                  \
        *(f32x4*)(hp[mti] + (size_t)(tcur) * 256) = hv;                       \
        const int m_ = w * 64 + mti * 16 + g * 4;                             \
        const int off_ = (m_ >> 3) * KGSTRIDE + r * 16 + (m_ & 7) * 2;        \
        uint2 pk_ = make_uint2(pack2(hv[0], hv[1]), pack2(hv[2], hv[3]));     \
        *(uint2*)(&Hlds[(BUF) ^ 1][off_]) = pk_;                              \
      }                                                                       \
    }                                                                         \
    asm volatile("s_waitcnt lgkmcnt(0)" ::: "memory");                        \
    __builtin_amdgcn_sched_barrier(0);                                        \
    __builtin_amdgcn_s_barrier();                                             \
    __builtin_amdgcn_sched_barrier(0);                                        \
  }

    for (int t = 0; t < T; t += 2) {
        SCAN_ONESTEP(0, cur0, t)
        SCAN_ONESTEP(1, cur1, t + 1)
    }
#undef SCAN_ONESTEP
}

// ---------------- elementwise gate ----------------
__global__ void ewise(const float* g, const float* __restrict__ big,
                      const float* __restrict__ x, float* ys, int n4)
{
    int i = blockIdx.x * blockDim.x + threadIdx.x;
    if (i >= n4) return;
    float4 gv = ((const float4*)g)[i];
    float4 bv = ((const float4*)big)[i];
    float4 xv = ((const float4*)x)[i];
    float4 r;
    r.x = gv.x * bv.x + (1.f - gv.x) * xv.x;
    r.y = gv.y * bv.y + (1.f - gv.y) * xv.y;
    r.z = gv.z * bv.z + (1.f - gv.z) * xv.z;
    r.w = gv.w * bv.w + (1.f - gv.w) * xv.w;
    ((float4*)ys)[i] = r;
}

extern "C" void kernel_launch(void* const* d_in, const int* in_sizes, int n_in,
                              void* d_out, int out_size, void* d_ws, size_t ws_size,
                              hipStream_t stream)
{
    const float* x      = (const float*)d_in[0];
    const float* W_in   = (const float*)d_in[1];
    const float* b_in   = (const float*)d_in[2];
    const float* W_gate = (const float*)d_in[3];
    const float* b_gate = (const float*)d_in[4];
    const float* Amat   = (const float*)d_in[5];
    const float* Bm     = (const float*)d_in[6];
    const float* Cm     = (const float*)d_in[7];
    const float* Dm     = (const float*)d_in[8];
    const float* W_out  = (const float*)d_in[9];
    const float* b_out  = (const float*)d_in[10];
    float* out = (float*)d_out;

    const int T = 2048, DM = 1024, DS = 256;
    const int M = 8 * T;  // 16384

    char* ws = (char*)d_ws;
    float* u   = (float*)(ws);
    float* u2  = (float*)(ws + (size_t)16 * 1024 * 1024);
    float* h   = (float*)(ws + (size_t)32 * 1024 * 1024);
    float* big = (float*)(ws + (size_t)48 * 1024 * 1024);
    float* g   = (float*)(ws + (size_t)112 * 1024 * 1024);

    dim3 blk(256);
    gemm64<E_BIAS, false><<<dim3(DS / 64, M / 64), blk, 0, stream>>>(
        x, W_in, b_in, nullptr, u, M, DS, DM);
    gemm64<E_NONE, true><<<dim3(DM / 64, M / 64), blk, 0, stream>>>(
        u, Dm, nullptr, nullptr, big, M, DM, DS);
    gemm64<E_NONE, false><<<dim3(DS / 64, M / 64), blk, 0, stream>>>(
        u, Bm, nullptr, nullptr, u2, M, DS, DS);
    gemm64<E_SIG, false><<<dim3(DM / 64, M / 64), blk, 0, stream>>>(
        x, W_gate, b_gate, nullptr, g, M, DM, DM);
    scan_mfma<<<1, 256, 0, stream>>>(Amat, u2, h);
    gemm64<E_ACC, true><<<dim3(DM / 64, M / 64), blk, 0, stream>>>(
        h, Cm, nullptr, nullptr, big, M, DM, DS);
    const int n4 = M * DM / 4;
    ewise<<<n4 / 256, 256, 0, stream>>>(g, big, x, g, n4);
    gemm64<E_BIASRES, false><<<dim3(DM / 64, M / 64), blk, 0, stream>>>(
        g, W_out, b_out, x, out, M, DM, DM);
}

// Round 4
// 3260.893 us; speedup vs baseline: 1.6169x; 1.6169x over previous
//
#include <hip/hip_runtime.h>
#include <math.h>

// MambaBlock: B=8, T=2048, D_MODEL=1024, D_STATE=256, all fp32.
//
// ws layout (176 MB):
//   u    = x @ W_in + b_in                      [16384,256] f32   ws +   0 MB
//   u2   = bf16(u @ Bm)                         [16384,256] bf16  ws +  16 MB
//   h    = scan(tanh(h@A + u2_t))               [16384,256] f32   ws +  32 MB
//   big  = u @ D^T  (+= h @ C^T later)          [16384,1024] f32  ws +  48 MB
//   g    = sigmoid(x @ W_gate + b_gate)         [16384,1024] f32  ws + 112 MB
//   out  = (g*big+(1-g)*x) @ W_out + b_out + x  d_out

enum { E_NONE = 0, E_BIAS = 1, E_SIG = 2, E_ACC = 3, E_BIASRES = 4, E_BF16 = 5 };

typedef __attribute__((ext_vector_type(8))) short bf16x8;
typedef __attribute__((ext_vector_type(4))) float f32x4;

static __device__ inline unsigned short f2bf(float f) {
    unsigned u = __builtin_bit_cast(unsigned, f);
    unsigned r = (u + 0x7fff + ((u >> 16) & 1)) >> 16;
    return (unsigned short)r;
}
static __device__ inline unsigned pack2(float a, float b) {
    return (unsigned)f2bf(a) | ((unsigned)f2bf(b) << 16);
}
static __device__ inline float bfhi(unsigned u) {          // high bf16 -> f32
    return __builtin_bit_cast(float, u & 0xffff0000u);
}
static __device__ inline float bflo(unsigned u) {          // low bf16 -> f32
    return __builtin_bit_cast(float, u << 16);
}
static __device__ inline float tanh_fast(float x) {
    float e = __builtin_amdgcn_exp2f(x * 2.8853900817779268f);
    float t = __builtin_amdgcn_rcpf(e + 1.0f);
    return fmaf(-2.0f, t, 1.0f);
}

// ---------------- fp32 tile GEMM ----------------
template <int EPI, bool BT>
__global__ __launch_bounds__(256) void gemm64(
    const float* __restrict__ Ag, const float* __restrict__ Bg,
    const float* __restrict__ bias, const float* __restrict__ res,
    float* Cg, int M, int N, int K)
{
    __shared__ float As[16][68];
    __shared__ float Bs[16][68];
    const int tid = threadIdx.x;
    const int m0 = blockIdx.y * 64, n0 = blockIdx.x * 64;
    const int tm = (tid >> 4) << 2;
    const int tn = (tid & 15) << 2;
    const int arow = tid >> 2;
    const int acol = (tid & 3) << 2;
    const int brow = tid >> 4;
    const int bcol = (tid & 15) << 2;
    float acc[4][4] = {};

    for (int k0 = 0; k0 < K; k0 += 16) {
        float4 a4 = *(const float4*)(Ag + (size_t)(m0 + arow) * K + k0 + acol);
        As[acol + 0][arow] = a4.x; As[acol + 1][arow] = a4.y;
        As[acol + 2][arow] = a4.z; As[acol + 3][arow] = a4.w;
        if (!BT) {
            float4 b4 = *(const float4*)(Bg + (size_t)(k0 + brow) * N + n0 + bcol);
            Bs[brow][bcol + 0] = b4.x; Bs[brow][bcol + 1] = b4.y;
            Bs[brow][bcol + 2] = b4.z; Bs[brow][bcol + 3] = b4.w;
        } else {
            float4 b4 = *(const float4*)(Bg + (size_t)(n0 + arow) * K + k0 + acol);
            Bs[acol + 0][arow] = b4.x; Bs[acol + 1][arow] = b4.y;
            Bs[acol + 2][arow] = b4.z; Bs[acol + 3][arow] = b4.w;
        }
        __syncthreads();
#pragma unroll
        for (int k = 0; k < 16; ++k) {
            float am[4], bv[4];
#pragma unroll
            for (int i = 0; i < 4; ++i) am[i] = As[k][tm + i];
#pragma unroll
            for (int j = 0; j < 4; ++j) bv[j] = Bs[k][tn + j];
#pragma unroll
            for (int i = 0; i < 4; ++i)
#pragma unroll
                for (int j = 0; j < 4; ++j)
                    acc[i][j] = fmaf(am[i], bv[j], acc[i][j]);
        }
        __syncthreads();
    }

#pragma unroll
    for (int i = 0; i < 4; ++i) {
        const int m = m0 + tm + i, n = n0 + tn;
        const size_t idx = (size_t)m * N + n;
        float4 v = make_float4(acc[i][0], acc[i][1], acc[i][2], acc[i][3]);
        if (EPI == E_BIAS || EPI == E_SIG || EPI == E_BIASRES) {
            v.x += bias[n + 0]; v.y += bias[n + 1];
            v.z += bias[n + 2]; v.w += bias[n + 3];
        }
        if (EPI == E_SIG) {
            v.x = 1.f / (1.f + expf(-v.x)); v.y = 1.f / (1.f + expf(-v.y));
            v.z = 1.f / (1.f + expf(-v.z)); v.w = 1.f / (1.f + expf(-v.w));
        }
        if (EPI == E_ACC) {
            float4 c = *(const float4*)(Cg + idx);
            v.x += c.x; v.y += c.y; v.z += c.z; v.w += c.w;
        }
        if (EPI == E_BIASRES) {
            float4 r = *(const float4*)(res + idx);
            v.x += r.x; v.y += r.y; v.z += r.z; v.w += r.w;
        }
        if (EPI == E_BF16) {
            ushort4 o;
            o.x = f2bf(v.x); o.y = f2bf(v.y); o.z = f2bf(v.z); o.w = f2bf(v.w);
            *(ushort4*)((unsigned short*)Cg + idx) = o;
        } else {
            *(float4*)(Cg + idx) = v;
        }
    }
}

// ---------------- MFMA scan, vmcnt-decoupled ----------------
// One block, 8 waves (512 thr). Wave w owns states [w*32, w*32+32).
// Per step: Y^T = A^T @ H^T (M=256, N=16 [8 real batches], K=256) via
// mfma_f32_16x16x32_bf16. A^T in regs (64 VGPR). H in LDS bf16,
// [2 buf][8 kt][32 slots][16B]; slot g*8+r8 holds states kt*32+g*8..+8 of
// batch r8. Lanes r>=8 read the SAME slot as r-8 (broadcast, free) -> B
// cols 8..15 duplicate cols 0..7, C cols 8..15 unused.
// Loop unrolled x4: h-store sources & u-load dests are 4-deep register
// rings -> compiler WAR/RAW vmcnt waits reference ~4-step-old ops (done).
// u2 read as bf16 (uint2 per mti) 4 steps ahead. Raw s_barrier +
// lgkmcnt(0): global loads/stores NEVER drained in the loop.
__global__ __launch_bounds__(512, 1) void scan_mfma(
    const float* __restrict__ Amat, const uint2* __restrict__ u2bf,
    float* __restrict__ hout)
{
    constexpr int T = 2048;
    __shared__ __align__(16) unsigned char H[2][8][32][16];

    const int tid = threadIdx.x;
    const int w = tid >> 6;        // 0..7
    const int l = tid & 63;
    const int r = l & 15;          // batch col (0..7 real) / A state row
    const int g = l >> 4;          // k-subgroup / C row-group
    const int r8 = r & 7;
    const bool act = (r < 8);
    const int m0 = w * 32;

    // zero H buf 0 (h_0 = 0)
    for (int i = tid; i < 8 * 32 * 16 / 4; i += 512)
        ((unsigned*)&H[0][0][0][0])[i] = 0u;

    // A^T fragments: lane holds A^T[m][k] = Amat[k][m],
    // m = m0 + mti*16 + r, k = kt*32 + g*8 + j.
    bf16x8 af[2][8];
#pragma unroll
    for (int mti = 0; mti < 2; ++mti) {
        const int m = m0 + mti * 16 + r;
#pragma unroll
        for (int kt = 0; kt < 8; ++kt) {
            unsigned wd[4];
#pragma unroll
            for (int jw = 0; jw < 4; ++jw) {
                const int k = kt * 32 + g * 8 + jw * 2;
                wd[jw] = pack2(Amat[(size_t)k * 256 + m],
                               Amat[(size_t)(k + 1) * 256 + m]);
            }
            af[mti][kt] = __builtin_bit_cast(bf16x8, *(uint4*)wd);
        }
    }

    // per-lane bases (act lanes only use them)
    size_t hbase[2], ubase[2];
#pragma unroll
    for (int mti = 0; mti < 2; ++mti) {
        const int mb = m0 + mti * 16 + g * 4;
        hbase[mti] = ((size_t)r * T) * 256 + mb;        // f32 elements
        ubase[mti] = ((size_t)r * T) * 64 + (mb >> 2);  // uint2 units
    }

    // u ring: 4 steps ahead
    uint2 ur[4][2] = {};
    if (act) {
#pragma unroll
        for (int i = 0; i < 4; ++i)
#pragma unroll
            for (int mti = 0; mti < 2; ++mti)
                ur[i][mti] = u2bf[ubase[mti] + (size_t)i * 64];
    }
    __syncthreads();

#define SCAN_STEP(I)                                                          \
  {                                                                           \
    constexpr int buf = (I) & 1;                                              \
    bf16x8 hf[8];                                                             \
    _Pragma("unroll")                                                         \
    for (int kt = 0; kt < 8; ++kt)                                            \
      hf[kt] = *(const bf16x8*)&H[buf][kt][g * 8 + r8][0];                    \
    f32x4 ps[2][2];                                                           \
    _Pragma("unroll")                                                         \
    for (int a = 0; a < 2; ++a)                                               \
      _Pragma("unroll")                                                       \
      for (int b = 0; b < 2; ++b) ps[a][b] = (f32x4){0.f, 0.f, 0.f, 0.f};     \
    _Pragma("unroll")                                                         \
    for (int kt = 0; kt < 4; ++kt) {                                          \
      ps[0][0] = __builtin_amdgcn_mfma_f32_16x16x32_bf16(af[0][kt], hf[kt],   \
                                                         ps[0][0], 0, 0, 0);  \
      ps[0][1] = __builtin_amdgcn_mfma_f32_16x16x32_bf16(                     \
          af[0][kt + 4], hf[kt + 4], ps[0][1], 0, 0, 0);                      \
      ps[1][0] = __builtin_amdgcn_mfma_f32_16x16x32_bf16(af[1][kt], hf[kt],   \
                                                         ps[1][0], 0, 0, 0);  \
      ps[1][1] = __builtin_amdgcn_mfma_f32_16x16x32_bf16(                     \
          af[1][kt + 4], hf[kt + 4], ps[1][1], 0, 0, 0);                      \
    }                                                                         \
    if (act) {                                                                \
      _Pragma("unroll")                                                       \
      for (int mti = 0; mti < 2; ++mti) {                                     \
        const int mb = m0 + mti * 16 + g * 4;                                 \
        const uint2 uv = ur[I][mti];                                          \
        float uu[4] = {bflo(uv.x), bfhi(uv.x), bflo(uv.y), bfhi(uv.y)};       \
        f32x4 hv;                                                             \
        _Pragma("unroll")                                                     \
        for (int q = 0; q < 4; ++q)                                           \
          hv[q] = tanh_fast(ps[mti][0][q] + ps[mti][1][q] + uu[q]);           \
        *(f32x4*)(hout + hbase[mti] + (size_t)(t + (I)) * 256) = hv;          \
        unsigned pk0, pk1;                                                    \
        asm("v_cvt_pk_bf16_f32 %0, %1, %2" : "=v"(pk0)                        \
            : "v"(hv[0]), "v"(hv[1]));                                        \
        asm("v_cvt_pk_bf16_f32 %0, %1, %2" : "=v"(pk1)                        \
            : "v"(hv[2]), "v"(hv[3]));                                        \
        *(uint2*)&H[buf ^ 1][mb >> 5][((mb >> 3) & 3) * 8 + r][(mb & 7) * 2] =\
            make_uint2(pk0, pk1);                                             \
        if (t + 4 + (I) < T)                                                  \
          ur[I][mti] = u2bf[ubase[mti] + (size_t)(t + 4 + (I)) * 64];         \
      }                                                                       \
    }                                                                         \
    asm volatile("s_waitcnt lgkmcnt(0)" ::: "memory");                        \
    __builtin_amdgcn_sched_barrier(0);                                        \
    __builtin_amdgcn_s_barrier();                                             \
    __builtin_amdgcn_sched_barrier(0);                                        \
  }

    for (int t = 0; t < T; t += 4) {
        SCAN_STEP(0)
        SCAN_STEP(1)
        SCAN_STEP(2)
        SCAN_STEP(3)
    }
#undef SCAN_STEP
}

// ---------------- elementwise gate ----------------
__global__ void ewise(const float* g, const float* __restrict__ big,
                      const float* __restrict__ x, float* ys, int n4)
{
    int i = blockIdx.x * blockDim.x + threadIdx.x;
    if (i >= n4) return;
    float4 gv = ((const float4*)g)[i];
    float4 bv = ((const float4*)big)[i];
    float4 xv = ((const float4*)x)[i];
    float4 r;
    r.x = gv.x * bv.x + (1.f - gv.x) * xv.x;
    r.y = gv.y * bv.y + (1.f - gv.y) * xv.y;
    r.z = gv.z * bv.z + (1.f - gv.z) * xv.z;
    r.w = gv.w * bv.w + (1.f - gv.w) * xv.w;
    ((float4*)ys)[i] = r;
}

extern "C" void kernel_launch(void* const* d_in, const int* in_sizes, int n_in,
                              void* d_out, int out_size, void* d_ws, size_t ws_size,
                              hipStream_t stream)
{
    const float* x      = (const float*)d_in[0];
    const float* W_in   = (const float*)d_in[1];
    const float* b_in   = (const float*)d_in[2];
    const float* W_gate = (const float*)d_in[3];
    const float* b_gate = (const float*)d_in[4];
    const float* Amat   = (const float*)d_in[5];
    const float* Bm     = (const float*)d_in[6];
    const float* Cm     = (const float*)d_in[7];
    const float* Dm     = (const float*)d_in[8];
    const float* W_out  = (const float*)d_in[9];
    const float* b_out  = (const float*)d_in[10];
    float* out = (float*)d_out;

    const int T = 2048, DM = 1024, DS = 256;
    const int M = 8 * T;  // 16384

    char* ws = (char*)d_ws;
    float* u    = (float*)(ws);
    float* u2   = (float*)(ws + (size_t)16 * 1024 * 1024);  // bf16 [16384,256]
    float* h    = (float*)(ws + (size_t)32 * 1024 * 1024);
    float* big  = (float*)(ws + (size_t)48 * 1024 * 1024);
    float* g    = (float*)(ws + (size_t)112 * 1024 * 1024);

    dim3 blk(256);
    gemm64<E_BIAS, false><<<dim3(DS / 64, M / 64), blk, 0, stream>>>(
        x, W_in, b_in, nullptr, u, M, DS, DM);
    gemm64<E_NONE, true><<<dim3(DM / 64, M / 64), blk, 0, stream>>>(
        u, Dm, nullptr, nullptr, big, M, DM, DS);
    gemm64<E_BF16, false><<<dim3(DS / 64, M / 64), blk, 0, stream>>>(
        u, Bm, nullptr, nullptr, u2, M, DS, DS);
    gemm64<E_SIG, false><<<dim3(DM / 64, M / 64), blk, 0, stream>>>(
        x, W_gate, b_gate, nullptr, g, M, DM, DM);
    scan_mfma<<<1, 512, 0, stream>>>(Amat, (const uint2*)u2, h);
    gemm64<E_ACC, true><<<dim3(DM / 64, M / 64), blk, 0, stream>>>(
        h, Cm, nullptr, nullptr, big, M, DM, DS);
    const int n4 = M * DM / 4;
    ewise<<<n4 / 256, 256, 0, stream>>>(g, big, x, g, n4);
    gemm64<E_BIASRES, false><<<dim3(DM / 64, M / 64), blk, 0, stream>>>(
        g, W_out, b_out, x, out, M, DM, DM);
}

// Round 5
// 3110.263 us; speedup vs baseline: 1.6952x; 1.0484x over previous
//
#include <hip/hip_runtime.h>
#include <math.h>

// MambaBlock: B=8, T=2048, D_MODEL=1024, D_STATE=256, all fp32.
//
// ws layout (176 MB):
//   u    = x @ W_in + b_in                      [16384,256] f32   ws +   0 MB
//   u2   = bf16(u @ Bm)                         [16384,256] bf16  ws +  16 MB
//   h    = scan(tanh(h@A + u2_t))               [16384,256] bf16  ws +  32 MB
//   big  = u @ D^T  (+= h @ C^T later)          [16384,1024] f32  ws +  48 MB
//   g    = sigmoid(x @ W_gate + b_gate)         [16384,1024] f32  ws + 112 MB
//   out  = (g*big+(1-g)*x) @ W_out + b_out + x  d_out

enum { E_NONE = 0, E_BIAS = 1, E_SIG = 2, E_ACC = 3, E_BIASRES = 4, E_BF16 = 5 };

typedef __attribute__((ext_vector_type(8))) short bf16x8;
typedef __attribute__((ext_vector_type(4))) float f32x4;

static __device__ inline unsigned short f2bf(float f) {
    unsigned u = __builtin_bit_cast(unsigned, f);
    unsigned r = (u + 0x7fff + ((u >> 16) & 1)) >> 16;
    return (unsigned short)r;
}
static __device__ inline unsigned pack2(float a, float b) {
    return (unsigned)f2bf(a) | ((unsigned)f2bf(b) << 16);
}
static __device__ inline float bfhi(unsigned u) {
    return __builtin_bit_cast(float, u & 0xffff0000u);
}
static __device__ inline float bflo(unsigned u) {
    return __builtin_bit_cast(float, u << 16);
}
static __device__ inline float bfu(unsigned short v) {
    return __builtin_bit_cast(float, (unsigned)v << 16);
}
static __device__ inline float tanh_fast(float x) {
    float e = __builtin_amdgcn_exp2f(x * 2.8853900817779268f);
    float t = __builtin_amdgcn_rcpf(e + 1.0f);
    return fmaf(-2.0f, t, 1.0f);
}

// ---------------- fp32 tile GEMM (ABF16: A operand stored as bf16) --------
template <int EPI, bool BT, bool ABF16 = false>
__global__ __launch_bounds__(256) void gemm64(
    const float* __restrict__ Ag, const float* __restrict__ Bg,
    const float* __restrict__ bias, const float* __restrict__ res,
    float* Cg, int M, int N, int K)
{
    __shared__ float As[16][68];
    __shared__ float Bs[16][68];
    const int tid = threadIdx.x;
    const int m0 = blockIdx.y * 64, n0 = blockIdx.x * 64;
    const int tm = (tid >> 4) << 2;
    const int tn = (tid & 15) << 2;
    const int arow = tid >> 2;
    const int acol = (tid & 3) << 2;
    const int brow = tid >> 4;
    const int bcol = (tid & 15) << 2;
    float acc[4][4] = {};

    for (int k0 = 0; k0 < K; k0 += 16) {
        if (ABF16) {
            ushort4 a4 = *(const ushort4*)((const unsigned short*)Ag +
                                           (size_t)(m0 + arow) * K + k0 + acol);
            As[acol + 0][arow] = bfu(a4.x); As[acol + 1][arow] = bfu(a4.y);
            As[acol + 2][arow] = bfu(a4.z); As[acol + 3][arow] = bfu(a4.w);
        } else {
            float4 a4 = *(const float4*)(Ag + (size_t)(m0 + arow) * K + k0 + acol);
            As[acol + 0][arow] = a4.x; As[acol + 1][arow] = a4.y;
            As[acol + 2][arow] = a4.z; As[acol + 3][arow] = a4.w;
        }
        if (!BT) {
            float4 b4 = *(const float4*)(Bg + (size_t)(k0 + brow) * N + n0 + bcol);
            Bs[brow][bcol + 0] = b4.x; Bs[brow][bcol + 1] = b4.y;
            Bs[brow][bcol + 2] = b4.z; Bs[brow][bcol + 3] = b4.w;
        } else {
            float4 b4 = *(const float4*)(Bg + (size_t)(n0 + arow) * K + k0 + acol);
            Bs[acol + 0][arow] = b4.x; Bs[acol + 1][arow] = b4.y;
            Bs[acol + 2][arow] = b4.z; Bs[acol + 3][arow] = b4.w;
        }
        __syncthreads();
#pragma unroll
        for (int k = 0; k < 16; ++k) {
            float am[4], bv[4];
#pragma unroll
            for (int i = 0; i < 4; ++i) am[i] = As[k][tm + i];
#pragma unroll
            for (int j = 0; j < 4; ++j) bv[j] = Bs[k][tn + j];
#pragma unroll
            for (int i = 0; i < 4; ++i)
#pragma unroll
                for (int j = 0; j < 4; ++j)
                    acc[i][j] = fmaf(am[i], bv[j], acc[i][j]);
        }
        __syncthreads();
    }

#pragma unroll
    for (int i = 0; i < 4; ++i) {
        const int m = m0 + tm + i, n = n0 + tn;
        const size_t idx = (size_t)m * N + n;
        float4 v = make_float4(acc[i][0], acc[i][1], acc[i][2], acc[i][3]);
        if (EPI == E_BIAS || EPI == E_SIG || EPI == E_BIASRES) {
            v.x += bias[n + 0]; v.y += bias[n + 1];
            v.z += bias[n + 2]; v.w += bias[n + 3];
        }
        if (EPI == E_SIG) {
            v.x = 1.f / (1.f + expf(-v.x)); v.y = 1.f / (1.f + expf(-v.y));
            v.z = 1.f / (1.f + expf(-v.z)); v.w = 1.f / (1.f + expf(-v.w));
        }
        if (EPI == E_ACC) {
            float4 c = *(const float4*)(Cg + idx);
            v.x += c.x; v.y += c.y; v.z += c.z; v.w += c.w;
        }
        if (EPI == E_BIASRES) {
            float4 r = *(const float4*)(res + idx);
            v.x += r.x; v.y += r.y; v.z += r.z; v.w += r.w;
        }
        if (EPI == E_BF16) {
            ushort4 o;
            o.x = f2bf(v.x); o.y = f2bf(v.y); o.z = f2bf(v.z); o.w = f2bf(v.w);
            *(ushort4*)((unsigned short*)Cg + idx) = o;
        } else {
            *(float4*)(Cg + idx) = v;
        }
    }
}

// ---------------- MFMA scan: zero global ops in the serial path ----------
// 8 waves (512 thr), wave w owns states [w*32,w*32+32). Per step:
// Y^T = A^T @ H^T (M=256,N=16[8 real],K=256) via mfma_f32_16x16x32_bf16.
// h lives in a 16-deep LDS ring H[16][8][32][16] (64 KiB): step t reads
// buf t&15 (h_{t-1}), writes buf (t+1)&15 (h_t). History dumped to global
// (bf16) every 4 steps with 8..11-step lag: conflict-free ds_read_b128 +
// fire-and-forget stores, overwrite hazard is 8+ barriers away.
// u2 batch-loaded 4 steps at a time, 4-7 steps ahead, into statically
// indexed register slots (x8 unroll => all indices compile-time).
__global__ __launch_bounds__(512, 2) void scan_mfma(
    const float* __restrict__ Amat, const uint2* __restrict__ u2bf,
    unsigned short* __restrict__ hbf)
{
    constexpr int T = 2048;
    __shared__ __align__(16) unsigned char H[16][8][32][16];

    const int tid = threadIdx.x;
    const int w = tid >> 6;
    const int l = tid & 63;
    const int r = l & 15;          // batch col (0..7 real)
    const int g = l >> 4;          // k-subgroup / C row-group
    const int r8 = r & 7;
    const bool act = (r < 8);
    const int m0 = w * 32;

    // zero ring buf 0 (h_{-1} = 0)
    for (int i = tid; i < 1024; i += 512)
        ((unsigned*)H)[i] = 0u;

    // A^T fragments: lane holds A^T[m][k] = Amat[k][m], m = m0+mti*16+r,
    // k = kt*32 + g*8 + j.
    bf16x8 af[2][8];
#pragma unroll
    for (int mti = 0; mti < 2; ++mti) {
        const int m = m0 + mti * 16 + r;
#pragma unroll
        for (int kt = 0; kt < 8; ++kt) {
            unsigned wd[4];
#pragma unroll
            for (int jw = 0; jw < 4; ++jw) {
                const int k = kt * 32 + g * 8 + jw * 2;
                wd[jw] = pack2(Amat[(size_t)k * 256 + m],
                               Amat[(size_t)(k + 1) * 256 + m]);
            }
            af[mti][kt] = __builtin_bit_cast(bf16x8, *(uint4*)wd);
        }
    }

    // u2 bases in uint2 units; use r8 so padding lanes load valid dups
    size_t ubase[2];
#pragma unroll
    for (int mti = 0; mti < 2; ++mti) {
        const int mb = m0 + mti * 16 + g * 4;
        ubase[mti] = ((size_t)r8 * T) * 64 + (mb >> 2);
    }

    // u ring: 2 slots x 4 steps x 2 mti (all indices compile-time)
    uint2 ur[2][4][2];
#pragma unroll
    for (int j = 0; j < 4; ++j)
#pragma unroll
        for (int mti = 0; mti < 2; ++mti)
            ur[0][j][mti] = u2bf[ubase[mti] + (size_t)j * 64];

    __syncthreads();

#define SCAN_STEP(I)                                                          \
  {                                                                           \
    const int tt = t + (I);                                                   \
    const unsigned br_ = ((unsigned)tt & 15u) * 4096u;                        \
    const unsigned bw_ = ((unsigned)(tt + 1) & 15u) * 4096u;                  \
    bf16x8 hf[8];                                                             \
    _Pragma("unroll")                                                         \
    for (int kt = 0; kt < 8; ++kt)                                            \
      hf[kt] = *(const bf16x8*)((unsigned char*)H + br_ +                     \
                                (unsigned)(kt * 32 + g * 8 + r8) * 16u);      \
    f32x4 ps[2][2];                                                           \
    _Pragma("unroll")                                                         \
    for (int a_ = 0; a_ < 2; ++a_)                                            \
      _Pragma("unroll")                                                       \
      for (int b_ = 0; b_ < 2; ++b_) ps[a_][b_] = (f32x4){0.f, 0.f, 0.f, 0.f};\
    _Pragma("unroll")                                                         \
    for (int kt = 0; kt < 4; ++kt) {                                          \
      ps[0][0] = __builtin_amdgcn_mfma_f32_16x16x32_bf16(af[0][kt], hf[kt],   \
                                                         ps[0][0], 0, 0, 0);  \
      ps[0][1] = __builtin_amdgcn_mfma_f32_16x16x32_bf16(                     \
          af[0][kt + 4], hf[kt + 4], ps[0][1], 0, 0, 0);                      \
      ps[1][0] = __builtin_amdgcn_mfma_f32_16x16x32_bf16(af[1][kt], hf[kt],   \
                                                         ps[1][0], 0, 0, 0);  \
      ps[1][1] = __builtin_amdgcn_mfma_f32_16x16x32_bf16(                     \
          af[1][kt + 4], hf[kt + 4], ps[1][1], 0, 0, 0);                      \
    }                                                                         \
    if ((I) == 0 && t + 4 < T) {                                              \
      _Pragma("unroll")                                                       \
      for (int j = 0; j < 4; ++j)                                             \
        _Pragma("unroll")                                                     \
        for (int mti = 0; mti < 2; ++mti)                                     \
          ur[1][j][mti] = u2bf[ubase[mti] + (size_t)(t + 4 + j) * 64];        \
    }                                                                         \
    if ((I) == 4 && t + 8 < T) {                                              \
      _Pragma("unroll")                                                       \
      for (int j = 0; j < 4; ++j)                                             \
        _Pragma("unroll")                                                     \
        for (int mti = 0; mti < 2; ++mti)                                     \
          ur[0][j][mti] = u2bf[ubase[mti] + (size_t)(t + 8 + j) * 64];        \
    }                                                                         \
    _Pragma("unroll")                                                         \
    for (int mti = 0; mti < 2; ++mti) {                                       \
      const int mb = m0 + mti * 16 + g * 4;                                   \
      const uint2 uv = ur[((I) >> 2) & 1][(I) & 3][mti];                      \
      float uu[4] = {bflo(uv.x), bfhi(uv.x), bflo(uv.y), bfhi(uv.y)};         \
      f32x4 hv;                                                               \
      _Pragma("unroll")                                                       \
      for (int q = 0; q < 4; ++q)                                             \
        hv[q] = tanh_fast(ps[mti][0][q] + ps[mti][1][q] + uu[q]);             \
      unsigned pk0, pk1;                                                      \
      asm("v_cvt_pk_bf16_f32 %0, %1, %2" : "=v"(pk0)                          \
          : "v"(hv[0]), "v"(hv[1]));                                          \
      asm("v_cvt_pk_bf16_f32 %0, %1, %2" : "=v"(pk1)                          \
          : "v"(hv[2]), "v"(hv[3]));                                          \
      if (act)                                                                \
        *(uint2*)((unsigned char*)H + bw_ +                                   \
                  (unsigned)((mb >> 5) * 32 + ((mb >> 3) & 3) * 8 + r) * 16u +\
                  (unsigned)(mb & 7) * 2u) = make_uint2(pk0, pk1);            \
    }                                                                         \
    if (((I) & 3) == 3 && tt >= 7) {                                          \
      _Pragma("unroll")                                                       \
      for (int half = 0; half < 2; ++half) {                                  \
        const int v_ = tid + half * 512;                                      \
        const int bi_ = v_ >> 8, wd_ = v_ & 255;                              \
        const int kt_ = wd_ >> 5, sl_ = wd_ & 31;                             \
        const unsigned bd_ = (unsigned)((tt - 6 + bi_) & 15) * 4096u;         \
        uint4 dat = *(const uint4*)((unsigned char*)H + bd_ +                 \
                                    (unsigned)wd_ * 16u);                     \
        const size_t off = ((size_t)((sl_ & 7) * T + (tt - 7 + bi_)) * 256 +  \
                            kt_ * 32 + (sl_ >> 3) * 8);                       \
        *(uint4*)(hbf + off) = dat;                                           \
      }                                                                       \
    }                                                                         \
    asm volatile("s_waitcnt lgkmcnt(0)" ::: "memory");                        \
    __builtin_amdgcn_sched_barrier(0);                                        \
    __builtin_amdgcn_s_barrier();                                             \
    __builtin_amdgcn_sched_barrier(0);                                        \
  }

    for (int t = 0; t < T; t += 8) {
        SCAN_STEP(0)
        SCAN_STEP(1)
        SCAN_STEP(2)
        SCAN_STEP(3)
        SCAN_STEP(4)
        SCAN_STEP(5)
        SCAN_STEP(6)
        SCAN_STEP(7)
    }
#undef SCAN_STEP

    // epilogue: dump remaining h_{2044..2047} (virtual tt = T+3)
    {
        const int tt = T + 3;
#pragma unroll
        for (int half = 0; half < 2; ++half) {
            const int v_ = tid + half * 512;
            const int bi_ = v_ >> 8, wd_ = v_ & 255;
            const int kt_ = wd_ >> 5, sl_ = wd_ & 31;
            const unsigned bd_ = (unsigned)((tt - 6 + bi_) & 15) * 4096u;
            uint4 dat = *(const uint4*)((unsigned char*)H + bd_ +
                                        (unsigned)wd_ * 16u);
            const size_t off = ((size_t)((sl_ & 7) * T + (tt - 7 + bi_)) * 256 +
                                kt_ * 32 + (sl_ >> 3) * 8);
            *(uint4*)(hbf + off) = dat;
        }
    }
}

// ---------------- elementwise gate ----------------
__global__ void ewise(const float* g, const float* __restrict__ big,
                      const float* __restrict__ x, float* ys, int n4)
{
    int i = blockIdx.x * blockDim.x + threadIdx.x;
    if (i >= n4) return;
    float4 gv = ((const float4*)g)[i];
    float4 bv = ((const float4*)big)[i];
    float4 xv = ((const float4*)x)[i];
    float4 r;
    r.x = gv.x * bv.x + (1.f - gv.x) * xv.x;
    r.y = gv.y * bv.y + (1.f - gv.y) * xv.y;
    r.z = gv.z * bv.z + (1.f - gv.z) * xv.z;
    r.w = gv.w * bv.w + (1.f - gv.w) * xv.w;
    ((float4*)ys)[i] = r;
}

extern "C" void kernel_launch(void* const* d_in, const int* in_sizes, int n_in,
                              void* d_out, int out_size, void* d_ws, size_t ws_size,
                              hipStream_t stream)
{
    const float* x      = (const float*)d_in[0];
    const float* W_in   = (const float*)d_in[1];
    const float* b_in   = (const float*)d_in[2];
    const float* W_gate = (const float*)d_in[3];
    const float* b_gate = (const float*)d_in[4];
    const float* Amat   = (const float*)d_in[5];
    const float* Bm     = (const float*)d_in[6];
    const float* Cm     = (const float*)d_in[7];
    const float* Dm     = (const float*)d_in[8];
    const float* W_out  = (const float*)d_in[9];
    const float* b_out  = (const float*)d_in[10];
    float* out = (float*)d_out;

    const int T = 2048, DM = 1024, DS = 256;
    const int M = 8 * T;  // 16384

    char* ws = (char*)d_ws;
    float* u    = (float*)(ws);
    float* u2   = (float*)(ws + (size_t)16 * 1024 * 1024);  // bf16 [16384,256]
    float* h    = (float*)(ws + (size_t)32 * 1024 * 1024);  // bf16 [16384,256]
    float* big  = (float*)(ws + (size_t)48 * 1024 * 1024);
    float* g    = (float*)(ws + (size_t)112 * 1024 * 1024);

    dim3 blk(256);
    gemm64<E_BIAS, false><<<dim3(DS / 64, M / 64), blk, 0, stream>>>(
        x, W_in, b_in, nullptr, u, M, DS, DM);
    gemm64<E_NONE, true><<<dim3(DM / 64, M / 64), blk, 0, stream>>>(
        u, Dm, nullptr, nullptr, big, M, DM, DS);
    gemm64<E_BF16, false><<<dim3(DS / 64, M / 64), blk, 0, stream>>>(
        u, Bm, nullptr, nullptr, u2, M, DS, DS);
    gemm64<E_SIG, false><<<dim3(DM / 64, M / 64), blk, 0, stream>>>(
        x, W_gate, b_gate, nullptr, g, M, DM, DM);
    scan_mfma<<<1, 512, 0, stream>>>(Amat, (const uint2*)u2,
                                     (unsigned short*)h);
    gemm64<E_ACC, true, true><<<dim3(DM / 64, M / 64), blk, 0, stream>>>(
        h, Cm, nullptr, nullptr, big, M, DM, DS);
    const int n4 = M * DM / 4;
    ewise<<<n4 / 256, 256, 0, stream>>>(g, big, x, g, n4);
    gemm64<E_BIASRES, false><<<dim3(DM / 64, M / 64), blk, 0, stream>>>(
        g, W_out, b_out, x, out, M, DM, DM);
}

// Round 6
// 1855.795 us; speedup vs baseline: 2.8411x; 1.6760x over previous
//
#include <hip/hip_runtime.h>
#include <math.h>

// MambaBlock: B=8, T=2048, D_MODEL=1024, D_STATE=256.
// All heavy GEMMs in bf16 MFMA; scan = 4-wave MFMA recurrence on 1 CU.
//
// ws layout (<=166 MB):
//   xbf/ysbf bf16 [16384,1024]  @   0 MB   (ysbf overwrites xbf after gate GEMM)
//   u    bf16 [16384,256]       @  32 MB
//   u2   f32  [16384,256]       @  40 MB
//   h    bf16 [16384,256]       @  56 MB
//   W_inT bf16 [256,1024]       @  64 MB
//   BmT  bf16 [256,256]         @  64.5 MB
//   W_gateT bf16 [1024,1024]    @  65 MB
//   W_outT  bf16 [1024,1024]    @  67 MB
//   Cbf  bf16 [1024,256]        @  69 MB
//   Dbf  bf16 [1024,256]        @  69.5 MB
//   big  f32  [16384,1024]      @  70 MB
//   gbf  bf16 [16384,1024]      @ 134 MB

enum { E_NONE = 0, E_BIASBF = 1, E_SIGBF = 2, E_ACC = 3, E_BIASRES = 4 };

typedef __attribute__((ext_vector_type(8))) short bf16x8;
typedef __attribute__((ext_vector_type(4))) float f32x4;

static __device__ inline unsigned short f2bf(float f) {
    unsigned u = __builtin_bit_cast(unsigned, f);
    unsigned r = (u + 0x7fff + ((u >> 16) & 1)) >> 16;
    return (unsigned short)r;
}
static __device__ inline unsigned pack2(float a, float b) {
    return (unsigned)f2bf(a) | ((unsigned)f2bf(b) << 16);
}
static __device__ inline float bflo(unsigned u) {
    return __builtin_bit_cast(float, u << 16);
}
static __device__ inline float bfhi(unsigned u) {
    return __builtin_bit_cast(float, u & 0xffff0000u);
}
static __device__ inline float tanh_fast(float x) {
    float e = __builtin_amdgcn_exp2f(x * 2.8853900817779268f);
    float t = __builtin_amdgcn_rcpf(e + 1.0f);
    return fmaf(-2.0f, t, 1.0f);
}

// ---------------- prepass: f32 -> bf16 convert ----------------
__global__ __launch_bounds__(256) void cvt_bf(
    const float* __restrict__ in, unsigned short* __restrict__ out, int n8)
{
    int i = blockIdx.x * 256 + threadIdx.x;
    if (i >= n8) return;
    float4 a = ((const float4*)in)[i * 2];
    float4 b = ((const float4*)in)[i * 2 + 1];
    uint4 o;
    o.x = pack2(a.x, a.y); o.y = pack2(a.z, a.w);
    o.z = pack2(b.x, b.y); o.w = pack2(b.z, b.w);
    ((uint4*)out)[i] = o;
}

// ---------------- prepass: f32 [R,C] -> bf16 [C,R] transpose ----------------
__global__ __launch_bounds__(256) void transpose_bf(
    const float* __restrict__ in, unsigned short* __restrict__ out, int R, int C)
{
    __shared__ float tile[32][33];
    const int bx = blockIdx.x * 32, by = blockIdx.y * 32;
    const int tx = threadIdx.x & 31, ty = threadIdx.x >> 5;  // ty 0..7
#pragma unroll
    for (int i = 0; i < 32; i += 8)
        tile[ty + i][tx] = in[(size_t)(by + ty + i) * C + bx + tx];
    __syncthreads();
#pragma unroll
    for (int i = 0; i < 32; i += 8)
        out[(size_t)(bx + ty + i) * R + by + tx] = f2bf(tile[tx][ty + i]);
}

// ---------------- bf16 MFMA GEMM: C[M,N] = A[M,K] * B[N,K]^T ----------------
// 128x128 tile, K-step 64, 4 waves. global_load_lds with XOR-swizzled source
// (rule #21: linear dest + inverse-swizzled source + swizzled ds_read).
// Fragment convention (scan-verified, m89): a(lane r,g)=A[r][g*8+j],
// b(lane r,g)=B^T[g*8+j][r]=Bst[r][g*8+j], D(lane r,g)[q]=C[g*4+q][r].
template <int EPI>
__global__ __launch_bounds__(256) void gemm_mfma(
    const unsigned short* __restrict__ Ag,  // [M,K] bf16
    const unsigned short* __restrict__ Bg,  // [N,K] bf16
    const float* __restrict__ bias, const float* __restrict__ res,
    void* Cg, int M, int N, int K)
{
    __shared__ __align__(16) unsigned char Lds[2][32768];  // [buf][A 16K | B 16K]
    const int tid = threadIdx.x;
    const int w = tid >> 6, l = tid & 63;
    const int r = l & 15, g = l >> 4;
    const int m0 = blockIdx.y * 128, n0 = blockIdx.x * 128;

    // staging: wave w covers LDS bytes [w*4096, +4096) of A and of B region.
    // chunk c = w*256 + j*64 + lane; row = c>>3; swizzle off' = off ^ 16*(row&7)
    const unsigned char* agp[4];
    const unsigned char* bgp[4];
#pragma unroll
    for (int j = 0; j < 4; ++j) {
        const int c = w * 256 + j * 64 + l;
        const int row = c >> 3;
        const unsigned offp = ((unsigned)(c & 7) * 16u) ^ ((unsigned)(row & 7) * 16u);
        agp[j] = (const unsigned char*)Ag + ((size_t)(m0 + row) * K) * 2 + offp;
        bgp[j] = (const unsigned char*)Bg + ((size_t)(n0 + row) * K) * 2 + offp;
    }

#define STAGE(BUF)                                                            \
    {                                                                         \
      _Pragma("unroll")                                                       \
      for (int j = 0; j < 4; ++j) {                                           \
        __builtin_amdgcn_global_load_lds(                                     \
            (const __attribute__((address_space(1))) unsigned*)(agp[j]),      \
            (__attribute__((address_space(3))) unsigned*)&Lds[(BUF)][w * 4096 + j * 1024], \
            16, 0, 0);                                                        \
        __builtin_amdgcn_global_load_lds(                                     \
            (const __attribute__((address_space(1))) unsigned*)(bgp[j]),      \
            (__attribute__((address_space(3))) unsigned*)&Lds[(BUF)][16384 + w * 4096 + j * 1024], \
            16, 0, 0);                                                        \
        agp[j] += 128; bgp[j] += 128;                                         \
      }                                                                       \
    }

    f32x4 acc[2][8];
#pragma unroll
    for (int mt = 0; mt < 2; ++mt)
#pragma unroll
        for (int nt = 0; nt < 8; ++nt) acc[mt][nt] = (f32x4){0.f, 0.f, 0.f, 0.f};

    const int nk = K >> 6;
    STAGE(0)
    __syncthreads();
    for (int t = 0; t < nk; ++t) {
        const int buf = t & 1;
        if (t + 1 < nk) { STAGE(buf ^ 1) }
        bf16x8 af[2][2], bf[8][2];
#pragma unroll
        for (int s = 0; s < 2; ++s) {
#pragma unroll
            for (int mt = 0; mt < 2; ++mt) {
                const int row = w * 32 + mt * 16 + r;
                af[mt][s] = *(const bf16x8*)&Lds[buf][row * 128 +
                    ((s * 64 + 16 * g) ^ (16 * (row & 7)))];
            }
#pragma unroll
            for (int nt = 0; nt < 8; ++nt) {
                const int row = nt * 16 + r;
                bf[nt][s] = *(const bf16x8*)&Lds[buf][16384 + row * 128 +
                    ((s * 64 + 16 * g) ^ (16 * (row & 7)))];
            }
        }
#pragma unroll
        for (int s = 0; s < 2; ++s)
#pragma unroll
            for (int mt = 0; mt < 2; ++mt)
#pragma unroll
                for (int nt = 0; nt < 8; ++nt)
                    acc[mt][nt] = __builtin_amdgcn_mfma_f32_16x16x32_bf16(
                        af[mt][s], bf[nt][s], acc[mt][nt], 0, 0, 0);
        __syncthreads();
    }
#undef STAGE

#pragma unroll
    for (int mt = 0; mt < 2; ++mt)
#pragma unroll
        for (int nt = 0; nt < 8; ++nt) {
            const int n = n0 + nt * 16 + r;
            float bv = 0.f;
            if (EPI == E_BIASBF || EPI == E_SIGBF || EPI == E_BIASRES) bv = bias[n];
#pragma unroll
            for (int q = 0; q < 4; ++q) {
                const int m = m0 + w * 32 + mt * 16 + g * 4 + q;
                const size_t idx = (size_t)m * N + n;
                float v = acc[mt][nt][q] + bv;
                if (EPI == E_SIGBF) v = 1.f / (1.f + expf(-v));
                if (EPI == E_ACC) v += ((const float*)Cg)[idx];
                if (EPI == E_BIASRES) v += res[idx];
                if (EPI == E_BIASBF || EPI == E_SIGBF)
                    ((unsigned short*)Cg)[idx] = f2bf(v);
                else
                    ((float*)Cg)[idx] = v;
            }
        }
}

// ---------------- MFMA scan: 4 waves, split-tanh, u as C-init ----------------
// Wave w owns states [w*64, w*64+64) (mt 0..3). Per step: Y^T = A^T @ H^T
// (M=256, N=16 [8 real batches], K=256). H in 16-deep LDS ring (64 KiB),
// [8 kt][32 slot][16B] per buffer; slot g*8+b = states kt*32+g*8..+8 of
// batch b; lanes r>=8 broadcast-read their twin (free). C cols 8..15
// duplicate 0..7, so lane r computes tanh for q in {0,1} and r+8 for {2,3}
// (halves VALU+trans), each writing disjoint b32 of the same slot.
// u2 (f32) enters as the MFMA C-initializer: no unpack, no add tail.
// History dumped to global (bf16) every 4 steps at lag 7..4 via
// conflict-free ds_read_b128 + fire-and-forget stores.
__global__ __launch_bounds__(256, 1) void scan_mfma(
    const float* __restrict__ Amat, const float* __restrict__ u2,
    unsigned short* __restrict__ hbf)
{
    constexpr int T = 2048;
    __shared__ __align__(16) unsigned char H[16][4096];

    const int tid = threadIdx.x;
    const int w = tid >> 6, l = tid & 63;
    const int r = l & 15, g = l >> 4, r8 = r & 7;
    const int qb = (r >> 3) << 1;  // 0 or 2
    const int m0 = w * 64;

    for (int i = tid; i < 1024; i += 256) ((unsigned*)H)[i] = 0u;  // h_{-1}=0

    // A^T frags: af[mt][kt](lane r,g) = Amat[kt*32+g*8+j][m0+mt*16+r]
    bf16x8 af[4][8];
#pragma unroll
    for (int mt = 0; mt < 4; ++mt) {
        const int m = m0 + mt * 16 + r;
#pragma unroll
        for (int kt = 0; kt < 8; ++kt) {
            unsigned wd[4];
#pragma unroll
            for (int jw = 0; jw < 4; ++jw) {
                const int k = kt * 32 + g * 8 + jw * 2;
                wd[jw] = pack2(Amat[(size_t)k * 256 + m],
                               Amat[(size_t)(k + 1) * 256 + m]);
            }
            af[mt][kt] = __builtin_bit_cast(bf16x8, *(uint4*)wd);
        }
    }

    const float* up[4];
#pragma unroll
    for (int mt = 0; mt < 4; ++mt)
        up[mt] = u2 + ((size_t)r8 * T) * 256 + (m0 + mt * 16 + g * 4);

    f32x4 ur[4][4];  // [step-in-group][mt], statically indexed
#pragma unroll
    for (int i = 0; i < 4; ++i)
#pragma unroll
        for (int mt = 0; mt < 4; ++mt)
            ur[i][mt] = *(const f32x4*)(up[mt] + (size_t)i * 256);

    __syncthreads();

#define SCAN_STEP(I)                                                          \
  {                                                                           \
    const int tt = t + (I);                                                   \
    const unsigned br_ = ((unsigned)tt & 15u) * 4096u;                        \
    const unsigned bw_ = ((unsigned)(tt + 1) & 15u) * 4096u;                  \
    bf16x8 hf[8];                                                             \
    _Pragma("unroll")                                                         \
    for (int kt = 0; kt < 8; ++kt)                                            \
      hf[kt] = *(const bf16x8*)((const unsigned char*)H + br_ +               \
                                (unsigned)(kt * 32 + g * 8 + r8) * 16u);      \
    f32x4 p0[4], p1[4];                                                       \
    _Pragma("unroll")                                                         \
    for (int mt = 0; mt < 4; ++mt) {                                          \
      p0[mt] = ur[I][mt];                                                     \
      p1[mt] = (f32x4){0.f, 0.f, 0.f, 0.f};                                   \
    }                                                                         \
    _Pragma("unroll")                                                         \
    for (int kt = 0; kt < 4; ++kt) {                                          \
      _Pragma("unroll")                                                       \
      for (int mt = 0; mt < 4; ++mt) {                                        \
        p0[mt] = __builtin_amdgcn_mfma_f32_16x16x32_bf16(af[mt][kt], hf[kt],  \
                                                         p0[mt], 0, 0, 0);    \
        p1[mt] = __builtin_amdgcn_mfma_f32_16x16x32_bf16(                     \
            af[mt][kt + 4], hf[kt + 4], p1[mt], 0, 0, 0);                     \
      }                                                                       \
    }                                                                         \
    if (tt + 4 < T) {                                                         \
      _Pragma("unroll")                                                       \
      for (int mt = 0; mt < 4; ++mt)                                          \
        ur[I][mt] = *(const f32x4*)(up[mt] + (size_t)(tt + 4) * 256);         \
    }                                                                         \
    _Pragma("unroll")                                                         \
    for (int mt = 0; mt < 4; ++mt) {                                          \
      const int mb = m0 + mt * 16 + g * 4;                                    \
      float h0 = tanh_fast(p0[mt][qb] + p1[mt][qb]);                          \
      float h1 = tanh_fast(p0[mt][qb + 1] + p1[mt][qb + 1]);                  \
      unsigned pk;                                                            \
      asm("v_cvt_pk_bf16_f32 %0, %1, %2" : "=v"(pk) : "v"(h0), "v"(h1));      \
      *(unsigned*)((unsigned char*)H + bw_ +                                  \
          (unsigned)((mb >> 5) * 32 + ((mb >> 3) & 3) * 8 + r8) * 16u +       \
          (unsigned)(((mb & 7) + qb) * 2)) = pk;                              \
    }                                                                         \
    if ((I) == 3 && tt >= 7) {                                                \
      _Pragma("unroll")                                                       \
      for (int cc = 0; cc < 4; ++cc) {                                        \
        const unsigned bd_ = (unsigned)((tt - 6 + cc) & 15) * 4096u;          \
        uint4 dat = *(const uint4*)((const unsigned char*)H + bd_ +           \
                                    (unsigned)tid * 16u);                     \
        const int kt_ = tid >> 5, sl_ = tid & 31;                             \
        const size_t off = ((size_t)((sl_ & 7) * T + (tt - 7 + cc)) * 256 +   \
                            kt_ * 32 + (sl_ >> 3) * 8);                       \
        *(uint4*)(hbf + off) = dat;                                           \
      }                                                                       \
    }                                                                         \
    asm volatile("s_waitcnt lgkmcnt(0)" ::: "memory");                        \
    __builtin_amdgcn_sched_barrier(0);                                        \
    __builtin_amdgcn_s_barrier();                                             \
    __builtin_amdgcn_sched_barrier(0);                                        \
  }

    for (int t = 0; t < T; t += 4) {
        SCAN_STEP(0)
        SCAN_STEP(1)
        SCAN_STEP(2)
        SCAN_STEP(3)
    }
#undef SCAN_STEP

    // epilogue: dump h_{2044..2047} (virtual tt = T+3)
    {
        const int tt = T + 3;
#pragma unroll
        for (int cc = 0; cc < 4; ++cc) {
            const unsigned bd_ = (unsigned)((tt - 6 + cc) & 15) * 4096u;
            uint4 dat = *(const uint4*)((const unsigned char*)H + bd_ +
                                        (unsigned)tid * 16u);
            const int kt_ = tid >> 5, sl_ = tid & 31;
            const size_t off = ((size_t)((sl_ & 7) * T + (tt - 7 + cc)) * 256 +
                                kt_ * 32 + (sl_ >> 3) * 8);
            *(uint4*)(hbf + off) = dat;
        }
    }
}

// ---------------- elementwise gate: ys = g*big + (1-g)*x (bf16 out) --------
__global__ __launch_bounds__(256) void ewise(
    const unsigned short* __restrict__ g8, const float* __restrict__ big,
    const float* __restrict__ x, unsigned short* __restrict__ ys, int n8)
{
    int i = blockIdx.x * 256 + threadIdx.x;
    if (i >= n8) return;
    uint4 gv = ((const uint4*)g8)[i];
    float4 b0 = ((const float4*)big)[i * 2], b1 = ((const float4*)big)[i * 2 + 1];
    float4 x0 = ((const float4*)x)[i * 2], x1 = ((const float4*)x)[i * 2 + 1];
    float gg[8] = {bflo(gv.x), bfhi(gv.x), bflo(gv.y), bfhi(gv.y),
                   bflo(gv.z), bfhi(gv.z), bflo(gv.w), bfhi(gv.w)};
    float bb[8] = {b0.x, b0.y, b0.z, b0.w, b1.x, b1.y, b1.z, b1.w};
    float xx[8] = {x0.x, x0.y, x0.z, x0.w, x1.x, x1.y, x1.z, x1.w};
    float yy[8];
#pragma unroll
    for (int k = 0; k < 8; ++k) yy[k] = gg[k] * bb[k] + (1.f - gg[k]) * xx[k];
    uint4 o;
    o.x = pack2(yy[0], yy[1]); o.y = pack2(yy[2], yy[3]);
    o.z = pack2(yy[4], yy[5]); o.w = pack2(yy[6], yy[7]);
    ((uint4*)ys)[i] = o;
}

extern "C" void kernel_launch(void* const* d_in, const int* in_sizes, int n_in,
                              void* d_out, int out_size, void* d_ws, size_t ws_size,
                              hipStream_t stream)
{
    const float* x      = (const float*)d_in[0];
    const float* W_in   = (const float*)d_in[1];
    const float* b_in   = (const float*)d_in[2];
    const float* W_gate = (const float*)d_in[3];
    const float* b_gate = (const float*)d_in[4];
    const float* Amat   = (const float*)d_in[5];
    const float* Bm     = (const float*)d_in[6];
    const float* Cm     = (const float*)d_in[7];
    const float* Dm     = (const float*)d_in[8];
    const float* W_out  = (const float*)d_in[9];
    const float* b_out  = (const float*)d_in[10];

    const int T = 2048, DM = 1024, DS = 256;
    const int M = 8 * T;  // 16384
    const size_t MB = 1024 * 1024;
    char* ws = (char*)d_ws;

    unsigned short* xbf  = (unsigned short*)(ws);
    unsigned short* ysbf = xbf;  // reuse after gate GEMM
    unsigned short* u    = (unsigned short*)(ws + 32 * MB);
    float*          u2   = (float*)(ws + 40 * MB);
    unsigned short* h    = (unsigned short*)(ws + 56 * MB);
    unsigned short* WinT = (unsigned short*)(ws + 64 * MB);
    unsigned short* BmT  = (unsigned short*)(ws + 64 * MB + 512 * 1024);
    unsigned short* WgT  = (unsigned short*)(ws + 65 * MB);
    unsigned short* WoT  = (unsigned short*)(ws + 67 * MB);
    unsigned short* Cbf  = (unsigned short*)(ws + 69 * MB);
    unsigned short* Dbf  = (unsigned short*)(ws + 69 * MB + 512 * 1024);
    float*          big  = (float*)(ws + 70 * MB);
    unsigned short* gbf  = (unsigned short*)(ws + 134 * MB);

    // prepass converts/transposes
    cvt_bf<<<M * DM / 8 / 256, 256, 0, stream>>>(x, xbf, M * DM / 8);
    transpose_bf<<<dim3(DS / 32, DM / 32), 256, 0, stream>>>(W_in, WinT, DM, DS);
    transpose_bf<<<dim3(DS / 32, DS / 32), 256, 0, stream>>>(Bm, BmT, DS, DS);
    transpose_bf<<<dim3(DM / 32, DM / 32), 256, 0, stream>>>(W_gate, WgT, DM, DM);
    transpose_bf<<<dim3(DM / 32, DM / 32), 256, 0, stream>>>(W_out, WoT, DM, DM);
    cvt_bf<<<DM * DS / 8 / 256, 256, 0, stream>>>(Cm, Cbf, DM * DS / 8);
    cvt_bf<<<DM * DS / 8 / 256, 256, 0, stream>>>(Dm, Dbf, DM * DS / 8);

    // u = bf16(x @ W_in + b_in)
    gemm_mfma<E_BIASBF><<<dim3(DS / 128, M / 128), 256, 0, stream>>>(
        xbf, WinT, b_in, nullptr, u, M, DS, DM);
    // big = u @ D^T
    gemm_mfma<E_NONE><<<dim3(DM / 128, M / 128), 256, 0, stream>>>(
        u, Dbf, nullptr, nullptr, big, M, DM, DS);
    // u2 = f32(u @ Bm)
    gemm_mfma<E_NONE><<<dim3(DS / 128, M / 128), 256, 0, stream>>>(
        u, BmT, nullptr, nullptr, u2, M, DS, DS);
    // g = bf16(sigmoid(x @ W_gate + b_gate))
    gemm_mfma<E_SIGBF><<<dim3(DM / 128, M / 128), 256, 0, stream>>>(
        xbf, WgT, b_gate, nullptr, gbf, M, DM, DM);
    // h recurrence
    scan_mfma<<<1, 256, 0, stream>>>(Amat, u2, h);
    // big += h @ C^T
    gemm_mfma<E_ACC><<<dim3(DM / 128, M / 128), 256, 0, stream>>>(
        h, Cbf, nullptr, nullptr, big, M, DM, DS);
    // ys = bf16(g*big + (1-g)*x)
    ewise<<<M * DM / 8 / 256, 256, 0, stream>>>(gbf, big, x, ysbf, M * DM / 8);
    // out = ys @ W_out + b_out + x
    gemm_mfma<E_BIASRES><<<dim3(DM / 128, M / 128), 256, 0, stream>>>(
        ysbf, WoT, b_out, x, (float*)d_out, M, DM, DM);
}

// Round 7
// 1699.848 us; speedup vs baseline: 3.1017x; 1.0917x over previous
//
#include <hip/hip_runtime.h>
#include <math.h>

// MambaBlock: B=8, T=2048, D_MODEL=1024, D_STATE=256.
// All heavy GEMMs in bf16 MFMA; scan = 4-wave chunked MFMA recurrence on 1 CU
// with a steady-state loop containing ZERO global-memory instructions.

enum { E_NONE = 0, E_BIASBF = 1, E_SIGBF = 2, E_ACC = 3, E_BIASRES = 4, E_CVTBF = 5 };

typedef __attribute__((ext_vector_type(8))) short bf16x8;
typedef __attribute__((ext_vector_type(4))) float f32x4;

static __device__ inline unsigned short f2bf(float f) {
    unsigned u = __builtin_bit_cast(unsigned, f);
    unsigned r = (u + 0x7fff + ((u >> 16) & 1)) >> 16;
    return (unsigned short)r;
}
static __device__ inline unsigned pack2(float a, float b) {
    return (unsigned)f2bf(a) | ((unsigned)f2bf(b) << 16);
}
static __device__ inline float bflo(unsigned u) {
    return __builtin_bit_cast(float, u << 16);
}
static __device__ inline float bfhi(unsigned u) {
    return __builtin_bit_cast(float, u & 0xffff0000u);
}
static __device__ inline float tanh_fast(float x) {
    float e = __builtin_amdgcn_exp2f(x * 2.8853900817779268f);
    float t = __builtin_amdgcn_rcpf(e + 1.0f);
    return fmaf(-2.0f, t, 1.0f);
}

// ---------------- prepass: f32 -> bf16 convert ----------------
__global__ __launch_bounds__(256) void cvt_bf(
    const float* __restrict__ in, unsigned short* __restrict__ out, int n8)
{
    int i = blockIdx.x * 256 + threadIdx.x;
    if (i >= n8) return;
    float4 a = ((const float4*)in)[i * 2];
    float4 b = ((const float4*)in)[i * 2 + 1];
    uint4 o;
    o.x = pack2(a.x, a.y); o.y = pack2(a.z, a.w);
    o.z = pack2(b.x, b.y); o.w = pack2(b.z, b.w);
    ((uint4*)out)[i] = o;
}

// ---------------- prepass: f32 [R,C] -> bf16 [C,R] transpose ----------------
__global__ __launch_bounds__(256) void transpose_bf(
    const float* __restrict__ in, unsigned short* __restrict__ out, int R, int C)
{
    __shared__ float tile[32][33];
    const int bx = blockIdx.x * 32, by = blockIdx.y * 32;
    const int tx = threadIdx.x & 31, ty = threadIdx.x >> 5;  // ty 0..7
#pragma unroll
    for (int i = 0; i < 32; i += 8)
        tile[ty + i][tx] = in[(size_t)(by + ty + i) * C + bx + tx];
    __syncthreads();
#pragma unroll
    for (int i = 0; i < 32; i += 8)
        out[(size_t)(bx + ty + i) * R + by + tx] = f2bf(tile[tx][ty + i]);
}

// ---------------- bf16 MFMA GEMM: C[M,N] = A[M,K] * B[N,K]^T ----------------
template <int EPI>
__global__ __launch_bounds__(256) void gemm_mfma(
    const unsigned short* __restrict__ Ag,  // [M,K] bf16
    const unsigned short* __restrict__ Bg,  // [N,K] bf16
    const float* __restrict__ bias, const float* __restrict__ res,
    void* Cg, int M, int N, int K)
{
    __shared__ __align__(16) unsigned char Lds[2][32768];  // [buf][A 16K | B 16K]
    const int tid = threadIdx.x;
    const int w = tid >> 6, l = tid & 63;
    const int r = l & 15, g = l >> 4;
    const int m0 = blockIdx.y * 128, n0 = blockIdx.x * 128;

    const unsigned char* agp[4];
    const unsigned char* bgp[4];
#pragma unroll
    for (int j = 0; j < 4; ++j) {
        const int c = w * 256 + j * 64 + l;
        const int row = c >> 3;
        const unsigned offp = ((unsigned)(c & 7) * 16u) ^ ((unsigned)(row & 7) * 16u);
        agp[j] = (const unsigned char*)Ag + ((size_t)(m0 + row) * K) * 2 + offp;
        bgp[j] = (const unsigned char*)Bg + ((size_t)(n0 + row) * K) * 2 + offp;
    }

#define STAGE(BUF)                                                            \
    {                                                                         \
      _Pragma("unroll")                                                       \
      for (int j = 0; j < 4; ++j) {                                           \
        __builtin_amdgcn_global_load_lds(                                     \
            (const __attribute__((address_space(1))) unsigned*)(agp[j]),      \
            (__attribute__((address_space(3))) unsigned*)&Lds[(BUF)][w * 4096 + j * 1024], \
            16, 0, 0);                                                        \
        __builtin_amdgcn_global_load_lds(                                     \
            (const __attribute__((address_space(1))) unsigned*)(bgp[j]),      \
            (__attribute__((address_space(3))) unsigned*)&Lds[(BUF)][16384 + w * 4096 + j * 1024], \
            16, 0, 0);                                                        \
        agp[j] += 128; bgp[j] += 128;                                         \
      }                                                                       \
    }

    f32x4 acc[2][8];
#pragma unroll
    for (int mt = 0; mt < 2; ++mt)
#pragma unroll
        for (int nt = 0; nt < 8; ++nt) acc[mt][nt] = (f32x4){0.f, 0.f, 0.f, 0.f};

    const int nk = K >> 6;
    STAGE(0)
    __syncthreads();
    for (int t = 0; t < nk; ++t) {
        const int buf = t & 1;
        if (t + 1 < nk) { STAGE(buf ^ 1) }
        bf16x8 af[2][2], bf[8][2];
#pragma unroll
        for (int s = 0; s < 2; ++s) {
#pragma unroll
            for (int mt = 0; mt < 2; ++mt) {
                const int row = w * 32 + mt * 16 + r;
                af[mt][s] = *(const bf16x8*)&Lds[buf][row * 128 +
                    ((s * 64 + 16 * g) ^ (16 * (row & 7)))];
            }
#pragma unroll
            for (int nt = 0; nt < 8; ++nt) {
                const int row = nt * 16 + r;
                bf[nt][s] = *(const bf16x8*)&Lds[buf][16384 + row * 128 +
                    ((s * 64 + 16 * g) ^ (16 * (row & 7)))];
            }
        }
#pragma unroll
        for (int s = 0; s < 2; ++s)
#pragma unroll
            for (int mt = 0; mt < 2; ++mt)
#pragma unroll
                for (int nt = 0; nt < 8; ++nt)
                    acc[mt][nt] = __builtin_amdgcn_mfma_f32_16x16x32_bf16(
                        af[mt][s], bf[nt][s], acc[mt][nt], 0, 0, 0);
        __syncthreads();
    }
#undef STAGE

#pragma unroll
    for (int mt = 0; mt < 2; ++mt)
#pragma unroll
        for (int nt = 0; nt < 8; ++nt) {
            const int n = n0 + nt * 16 + r;
            float bv = 0.f;
            if (EPI == E_BIASBF || EPI == E_SIGBF || EPI == E_BIASRES) bv = bias[n];
#pragma unroll
            for (int q = 0; q < 4; ++q) {
                const int m = m0 + w * 32 + mt * 16 + g * 4 + q;
                const size_t idx = (size_t)m * N + n;
                float v = acc[mt][nt][q] + bv;
                if (EPI == E_SIGBF) v = 1.f / (1.f + expf(-v));
                if (EPI == E_ACC) v += ((const float*)Cg)[idx];
                if (EPI == E_BIASRES) v += res[idx];
                if (EPI == E_BIASBF || EPI == E_SIGBF || EPI == E_CVTBF)
                    ((unsigned short*)Cg)[idx] = f2bf(v);
                else
                    ((float*)Cg)[idx] = v;
            }
        }
}

// ---------------- chunked MFMA scan: zero vmem in the serial path ----------
// 4 waves. Wave w owns states [w*64, w*64+64). Per step: Y^T = A^T @ H^T
// (M=256, N=16 [8 real], K=256) via mfma_f32_16x16x32_bf16, A^T in regs.
// H in 16-deep LDS ring (64 KiB). u2 (bf16) staged per 8-step chunk into
// double-buffered LDS (2x32 KiB) via global_load_lds with granule-XOR-
// swizzled per-lane SOURCE (conflict-free b32 reads; rule #21). h history
// dumped at chunk end (lag 8..15) via ds_read_b128 + fire-and-forget
// global_store. Exactly ONE counted vmcnt(8) wait per chunk, never 0.
__global__ __launch_bounds__(256, 1) void scan_mfma(
    const float* __restrict__ Amat, const unsigned short* __restrict__ u2bf,
    unsigned short* __restrict__ hbf)
{
    constexpr int T = 2048;
    __shared__ __align__(16) unsigned char LDSM[64 * 1024 + 2 * 32 * 1024];
    unsigned char* Hb = LDSM;              // ring: [16][4096]
    unsigned char* Ub = LDSM + 65536;      // [2][8 steps][8 batches][512 B]

    const int tid = threadIdx.x;
    const int w = tid >> 6, l = tid & 63;
    const int r = l & 15, g = l >> 4, r8 = r & 7;
    const int qb = (r >> 3) << 1;  // 0 or 2
    const int m0 = w * 64;

    for (int i = tid; i < 1024; i += 256) ((unsigned*)Hb)[i] = 0u;  // h_{-1}=0

    // A^T frags: af[mt][kt](lane r,g) = Amat[kt*32+g*8+j][m0+mt*16+r]
    bf16x8 af[4][8];
#pragma unroll
    for (int mt = 0; mt < 4; ++mt) {
        const int m = m0 + mt * 16 + r;
#pragma unroll
        for (int kt = 0; kt < 8; ++kt) {
            unsigned wd[4];
#pragma unroll
            for (int jw = 0; jw < 4; ++jw) {
                const int k = kt * 32 + g * 8 + jw * 2;
                wd[jw] = pack2(Amat[(size_t)k * 256 + m],
                               Amat[(size_t)(k + 1) * 256 + m]);
            }
            af[mt][kt] = __builtin_bit_cast(bf16x8, *(uint4*)wd);
        }
    }

    // per-lane u-read byte offsets within a U buffer (granule-XOR layout)
    unsigned uoff[4];
#pragma unroll
    for (int mt = 0; mt < 4; ++mt) {
        const int state = m0 + mt * 16 + g * 4 + qb;
        const int gran = state >> 3;
        uoff[mt] = (unsigned)(r8 * 512 + ((gran ^ r8) * 16) + ((state & 7) * 2));
    }

    // u staging source pointers (inverse-swizzled global source)
    const unsigned char* usrc[8];
#pragma unroll
    for (int j = 0; j < 8; ++j) {
        const int flat = j * 256 + tid;
        const int ri = flat >> 5, s = ri >> 3, b = ri & 7, gp = flat & 31;
        usrc[j] = (const unsigned char*)u2bf + ((size_t)(b * T + s) * 512)
                + (unsigned)((gp ^ b) * 16);
    }

    // prologue: stage chunk 0 into U buf 0
#pragma unroll
    for (int j = 0; j < 8; ++j) {
        __builtin_amdgcn_global_load_lds(
            (const __attribute__((address_space(1))) unsigned*)(usrc[j]),
            (__attribute__((address_space(3))) unsigned*)(Ub + (j * 256 + tid) * 16),
            16, 0, 0);
        usrc[j] += 4096;
    }
    asm volatile("s_waitcnt vmcnt(0) lgkmcnt(0)" ::: "memory");
    __builtin_amdgcn_sched_barrier(0);
    __builtin_amdgcn_s_barrier();
    __builtin_amdgcn_sched_barrier(0);

#define SCAN_STEP(I)                                                          \
  {                                                                           \
    const int tt = t0 + (I);                                                  \
    const unsigned br_ = ((unsigned)tt & 15u) * 4096u;                        \
    const unsigned bw_ = ((unsigned)(tt + 1) & 15u) * 4096u;                  \
    bf16x8 hf[8];                                                             \
    _Pragma("unroll")                                                         \
    for (int kt = 0; kt < 8; ++kt)                                            \
      hf[kt] = *(const bf16x8*)(Hb + br_ +                                    \
                                (unsigned)(kt * 32 + g * 8 + r8) * 16u);      \
    unsigned uval[4];                                                         \
    _Pragma("unroll")                                                         \
    for (int mt = 0; mt < 4; ++mt)                                            \
      uval[mt] = *(const unsigned*)(Ub + ubuf_ + (unsigned)(I) * 4096u +      \
                                    uoff[mt]);                                \
    asm volatile("s_waitcnt lgkmcnt(0)" ::: "memory");                        \
    __builtin_amdgcn_sched_barrier(0);                                        \
    f32x4 p0[4], p1[4];                                                       \
    _Pragma("unroll")                                                         \
    for (int mt = 0; mt < 4; ++mt) {                                          \
      p0[mt] = (f32x4){0.f, 0.f, 0.f, 0.f};                                   \
      p1[mt] = (f32x4){0.f, 0.f, 0.f, 0.f};                                   \
    }                                                                         \
    _Pragma("unroll")                                                         \
    for (int kt = 0; kt < 4; ++kt) {                                          \
      _Pragma("unroll")                                                       \
      for (int mt = 0; mt < 4; ++mt) {                                        \
        p0[mt] = __builtin_amdgcn_mfma_f32_16x16x32_bf16(af[mt][kt], hf[kt],  \
                                                         p0[mt], 0, 0, 0);    \
        p1[mt] = __builtin_amdgcn_mfma_f32_16x16x32_bf16(                     \
            af[mt][kt + 4], hf[kt + 4], p1[mt], 0, 0, 0);                     \
      }                                                                       \
    }                                                                         \
    _Pragma("unroll")                                                         \
    for (int mt = 0; mt < 4; ++mt) {                                          \
      const int mb = m0 + mt * 16 + g * 4;                                    \
      float s0 = p0[mt][qb] + p1[mt][qb] + bflo(uval[mt]);                    \
      float s1 = p0[mt][qb + 1] + p1[mt][qb + 1] + bfhi(uval[mt]);            \
      float h0 = tanh_fast(s0), h1 = tanh_fast(s1);                           \
      unsigned pk;                                                            \
      asm("v_cvt_pk_bf16_f32 %0, %1, %2" : "=v"(pk) : "v"(h0), "v"(h1));      \
      *(unsigned*)(Hb + bw_ +                                                 \
          (unsigned)((mb >> 5) * 32 + ((mb >> 3) & 3) * 8 + r8) * 16u +       \
          (unsigned)(((mb & 7) + qb) * 2)) = pk;                              \
    }                                                                         \
    if ((I) == 7 && t0 > 0) {                                                 \
      _Pragma("unroll")                                                       \
      for (int cc = 0; cc < 8; ++cc) {                                        \
        const unsigned bd_ = (unsigned)((t0 - 7 + cc) & 15) * 4096u;          \
        uint4 dat = *(const uint4*)(Hb + bd_ + (unsigned)tid * 16u);          \
        const int kt_ = tid >> 5, sl_ = tid & 31;                             \
        const size_t off = ((size_t)((sl_ & 7) * T + (t0 - 8 + cc)) * 256 +   \
                            kt_ * 32 + (sl_ >> 3) * 8);                       \
        *(uint4*)(hbf + off) = dat;                                           \
      }                                                                       \
    }                                                                         \
    asm volatile("s_waitcnt lgkmcnt(0)" ::: "memory");                        \
    __builtin_amdgcn_sched_barrier(0);                                        \
    if ((I) == 7) {                                                           \
      asm volatile("s_waitcnt vmcnt(8)" ::: "memory");                        \
      __builtin_amdgcn_sched_barrier(0);                                      \
    }                                                                         \
    __builtin_amdgcn_s_barrier();                                             \
    __builtin_amdgcn_sched_barrier(0);                                        \
  }

    for (int t0 = 0; t0 < T; t0 += 8) {
        const unsigned ubuf_ = (unsigned)((t0 >> 3) & 1) * 32768u;
        // stage next chunk into the other U buffer (fire-and-forget)
        if (t0 + 8 < T) {
            const unsigned nb_ = ubuf_ ^ 32768u;
#pragma unroll
            for (int j = 0; j < 8; ++j) {
                __builtin_amdgcn_global_load_lds(
                    (const __attribute__((address_space(1))) unsigned*)(usrc[j]),
                    (__attribute__((address_space(3))) unsigned*)(Ub + nb_ + (j * 256 + tid) * 16),
                    16, 0, 0);
                usrc[j] += 4096;
            }
        }
        SCAN_STEP(0)
        SCAN_STEP(1)
        SCAN_STEP(2)
        SCAN_STEP(3)
        SCAN_STEP(4)
        SCAN_STEP(5)
        SCAN_STEP(6)
        SCAN_STEP(7)
    }
#undef SCAN_STEP

    // epilogue: dump h_{2040..2047} (slots (2041..2048)&15)
    {
#pragma unroll
        for (int cc = 0; cc < 8; ++cc) {
            const unsigned bd_ = (unsigned)((T - 7 + cc) & 15) * 4096u;
            uint4 dat = *(const uint4*)(Hb + bd_ + (unsigned)tid * 16u);
            const int kt_ = tid >> 5, sl_ = tid & 31;
            const size_t off = ((size_t)((sl_ & 7) * T + (T - 8 + cc)) * 256 +
                                kt_ * 32 + (sl_ >> 3) * 8);
            *(uint4*)(hbf + off) = dat;
        }
    }
}

// ---------------- elementwise gate: ys = g*big + (1-g)*x (bf16 out) --------
__global__ __launch_bounds__(256) void ewise(
    const unsigned short* __restrict__ g8, const float* __restrict__ big,
    const float* __restrict__ x, unsigned short* __restrict__ ys, int n8)
{
    int i = blockIdx.x * 256 + threadIdx.x;
    if (i >= n8) return;
    uint4 gv = ((const uint4*)g8)[i];
    float4 b0 = ((const float4*)big)[i * 2], b1 = ((const float4*)big)[i * 2 + 1];
    float4 x0 = ((const float4*)x)[i * 2], x1 = ((const float4*)x)[i * 2 + 1];
    float gg[8] = {bflo(gv.x), bfhi(gv.x), bflo(gv.y), bfhi(gv.y),
                   bflo(gv.z), bfhi(gv.z), bflo(gv.w), bfhi(gv.w)};
    float bb[8] = {b0.x, b0.y, b0.z, b0.w, b1.x, b1.y, b1.z, b1.w};
    float xx[8] = {x0.x, x0.y, x0.z, x0.w, x1.x, x1.y, x1.z, x1.w};
    float yy[8];
#pragma unroll
    for (int k = 0; k < 8; ++k) yy[k] = gg[k] * bb[k] + (1.f - gg[k]) * xx[k];
    uint4 o;
    o.x = pack2(yy[0], yy[1]); o.y = pack2(yy[2], yy[3]);
    o.z = pack2(yy[4], yy[5]); o.w = pack2(yy[6], yy[7]);
    ((uint4*)ys)[i] = o;
}

extern "C" void kernel_launch(void* const* d_in, const int* in_sizes, int n_in,
                              void* d_out, int out_size, void* d_ws, size_t ws_size,
                              hipStream_t stream)
{
    const float* x      = (const float*)d_in[0];
    const float* W_in   = (const float*)d_in[1];
    const float* b_in   = (const float*)d_in[2];
    const float* W_gate = (const float*)d_in[3];
    const float* b_gate = (const float*)d_in[4];
    const float* Amat   = (const float*)d_in[5];
    const float* Bm     = (const float*)d_in[6];
    const float* Cm     = (const float*)d_in[7];
    const float* Dm     = (const float*)d_in[8];
    const float* W_out  = (const float*)d_in[9];
    const float* b_out  = (const float*)d_in[10];

    const int T = 2048, DM = 1024, DS = 256;
    const int M = 8 * T;  // 16384
    const size_t MB = 1024 * 1024;
    char* ws = (char*)d_ws;

    unsigned short* xbf  = (unsigned short*)(ws);
    unsigned short* ysbf = xbf;  // reuse after gate GEMM
    unsigned short* u    = (unsigned short*)(ws + 32 * MB);
    unsigned short* u2   = (unsigned short*)(ws + 40 * MB);  // bf16 [16384,256]
    unsigned short* h    = (unsigned short*)(ws + 56 * MB);  // bf16 [16384,256]
    unsigned short* WinT = (unsigned short*)(ws + 64 * MB);
    unsigned short* BmT  = (unsigned short*)(ws + 64 * MB + 512 * 1024);
    unsigned short* WgT  = (unsigned short*)(ws + 65 * MB);
    unsigned short* WoT  = (unsigned short*)(ws + 67 * MB);
    unsigned short* Cbf  = (unsigned short*)(ws + 69 * MB);
    unsigned short* Dbf  = (unsigned short*)(ws + 69 * MB + 512 * 1024);
    float*          big  = (float*)(ws + 70 * MB);
    unsigned short* gbf  = (unsigned short*)(ws + 134 * MB);

    // prepass converts/transposes
    cvt_bf<<<M * DM / 8 / 256, 256, 0, stream>>>(x, xbf, M * DM / 8);
    transpose_bf<<<dim3(DS / 32, DM / 32), 256, 0, stream>>>(W_in, WinT, DM, DS);
    transpose_bf<<<dim3(DS / 32, DS / 32), 256, 0, stream>>>(Bm, BmT, DS, DS);
    transpose_bf<<<dim3(DM / 32, DM / 32), 256, 0, stream>>>(W_gate, WgT, DM, DM);
    transpose_bf<<<dim3(DM / 32, DM / 32), 256, 0, stream>>>(W_out, WoT, DM, DM);
    cvt_bf<<<DM * DS / 8 / 256, 256, 0, stream>>>(Cm, Cbf, DM * DS / 8);
    cvt_bf<<<DM * DS / 8 / 256, 256, 0, stream>>>(Dm, Dbf, DM * DS / 8);

    // u = bf16(x @ W_in + b_in)
    gemm_mfma<E_BIASBF><<<dim3(DS / 128, M / 128), 256, 0, stream>>>(
        xbf, WinT, b_in, nullptr, u, M, DS, DM);
    // big = u @ D^T
    gemm_mfma<E_NONE><<<dim3(DM / 128, M / 128), 256, 0, stream>>>(
        u, Dbf, nullptr, nullptr, big, M, DM, DS);
    // u2 = bf16(u @ Bm)
    gemm_mfma<E_CVTBF><<<dim3(DS / 128, M / 128), 256, 0, stream>>>(
        u, BmT, nullptr, nullptr, u2, M, DS, DS);
    // g = bf16(sigmoid(x @ W_gate + b_gate))
    gemm_mfma<E_SIGBF><<<dim3(DM / 128, M / 128), 256, 0, stream>>>(
        xbf, WgT, b_gate, nullptr, gbf, M, DM, DM);
    // h recurrence
    scan_mfma<<<1, 256, 0, stream>>>(Amat, u2, h);
    // big += h @ C^T
    gemm_mfma<E_ACC><<<dim3(DM / 128, M / 128), 256, 0, stream>>>(
        h, Cbf, nullptr, nullptr, big, M, DM, DS);
    // ys = bf16(g*big + (1-g)*x)
    ewise<<<M * DM / 8 / 256, 256, 0, stream>>>(gbf, big, x, ysbf, M * DM / 8);
    // out = ys @ W_out + b_out + x
    gemm_mfma<E_BIASRES><<<dim3(DM / 128, M / 128), 256, 0, stream>>>(
        ysbf, WoT, b_out, x, (float*)d_out, M, DM, DM);
}

// Round 8
// 1559.331 us; speedup vs baseline: 3.3812x; 1.0901x over previous
//
#include <hip/hip_runtime.h>
#include <math.h>

// MambaBlock: B=8, T=2048, D_MODEL=1024, D_STATE=256.
// GEMMs: bf16 MFMA 128x128 tiles. Scan: 8 blocks (one per batch, 8 CUs),
// 4 waves each, MFMA recurrence with broadcast-h LDS and zero vmem in the
// serial path.

enum { E_NONE = 0, E_BIASBF = 1, E_SIGBF = 2, E_ACC = 3, E_BIASRES = 4, E_CVTBF = 5 };

typedef __attribute__((ext_vector_type(8))) short bf16x8;
typedef __attribute__((ext_vector_type(4))) float f32x4;

static __device__ inline unsigned short f2bf(float f) {
    unsigned u = __builtin_bit_cast(unsigned, f);
    unsigned r = (u + 0x7fff + ((u >> 16) & 1)) >> 16;
    return (unsigned short)r;
}
static __device__ inline unsigned pack2(float a, float b) {
    return (unsigned)f2bf(a) | ((unsigned)f2bf(b) << 16);
}
static __device__ inline float bflo(unsigned u) {
    return __builtin_bit_cast(float, u << 16);
}
static __device__ inline float bfhi(unsigned u) {
    return __builtin_bit_cast(float, u & 0xffff0000u);
}
static __device__ inline float tanh_fast(float x) {
    float e = __builtin_amdgcn_exp2f(x * 2.8853900817779268f);
    float t = __builtin_amdgcn_rcpf(e + 1.0f);
    return fmaf(-2.0f, t, 1.0f);
}

// ---------------- prepass: f32 -> bf16 convert ----------------
__global__ __launch_bounds__(256) void cvt_bf(
    const float* __restrict__ in, unsigned short* __restrict__ out, int n8)
{
    int i = blockIdx.x * 256 + threadIdx.x;
    if (i >= n8) return;
    float4 a = ((const float4*)in)[i * 2];
    float4 b = ((const float4*)in)[i * 2 + 1];
    uint4 o;
    o.x = pack2(a.x, a.y); o.y = pack2(a.z, a.w);
    o.z = pack2(b.x, b.y); o.w = pack2(b.z, b.w);
    ((uint4*)out)[i] = o;
}

// ---------------- prepass: f32 [R,C] -> bf16 [C,R] transpose ----------------
__global__ __launch_bounds__(256) void transpose_bf(
    const float* __restrict__ in, unsigned short* __restrict__ out, int R, int C)
{
    __shared__ float tile[32][33];
    const int bx = blockIdx.x * 32, by = blockIdx.y * 32;
    const int tx = threadIdx.x & 31, ty = threadIdx.x >> 5;  // ty 0..7
#pragma unroll
    for (int i = 0; i < 32; i += 8)
        tile[ty + i][tx] = in[(size_t)(by + ty + i) * C + bx + tx];
    __syncthreads();
#pragma unroll
    for (int i = 0; i < 32; i += 8)
        out[(size_t)(bx + ty + i) * R + by + tx] = f2bf(tile[tx][ty + i]);
}

// ---------------- bf16 MFMA GEMM: C[M,N] = A[M,K] * B[N,K]^T ----------------
template <int EPI>
__global__ __launch_bounds__(256) void gemm_mfma(
    const unsigned short* __restrict__ Ag,  // [M,K] bf16
    const unsigned short* __restrict__ Bg,  // [N,K] bf16
    const float* __restrict__ bias, const float* __restrict__ res,
    void* Cg, int M, int N, int K)
{
    __shared__ __align__(16) unsigned char Lds[2][32768];  // [buf][A 16K | B 16K]
    const int tid = threadIdx.x;
    const int w = tid >> 6, l = tid & 63;
    const int r = l & 15, g = l >> 4;
    const int m0 = blockIdx.y * 128, n0 = blockIdx.x * 128;

    const unsigned char* agp[4];
    const unsigned char* bgp[4];
#pragma unroll
    for (int j = 0; j < 4; ++j) {
        const int c = w * 256 + j * 64 + l;
        const int row = c >> 3;
        const unsigned offp = ((unsigned)(c & 7) * 16u) ^ ((unsigned)(row & 7) * 16u);
        agp[j] = (const unsigned char*)Ag + ((size_t)(m0 + row) * K) * 2 + offp;
        bgp[j] = (const unsigned char*)Bg + ((size_t)(n0 + row) * K) * 2 + offp;
    }

#define STAGE(BUF)                                                            \
    {                                                                         \
      _Pragma("unroll")                                                       \
      for (int j = 0; j < 4; ++j) {                                           \
        __builtin_amdgcn_global_load_lds(                                     \
            (const __attribute__((address_space(1))) unsigned*)(agp[j]),      \
            (__attribute__((address_space(3))) unsigned*)&Lds[(BUF)][w * 4096 + j * 1024], \
            16, 0, 0);                                                        \
        __builtin_amdgcn_global_load_lds(                                     \
            (const __attribute__((address_space(1))) unsigned*)(bgp[j]),      \
            (__attribute__((address_space(3))) unsigned*)&Lds[(BUF)][16384 + w * 4096 + j * 1024], \
            16, 0, 0);                                                        \
        agp[j] += 128; bgp[j] += 128;                                         \
      }                                                                       \
    }

    f32x4 acc[2][8];
#pragma unroll
    for (int mt = 0; mt < 2; ++mt)
#pragma unroll
        for (int nt = 0; nt < 8; ++nt) acc[mt][nt] = (f32x4){0.f, 0.f, 0.f, 0.f};

    const int nk = K >> 6;
    STAGE(0)
    __syncthreads();
    for (int t = 0; t < nk; ++t) {
        const int buf = t & 1;
        if (t + 1 < nk) { STAGE(buf ^ 1) }
        bf16x8 af[2][2], bfr[8][2];
#pragma unroll
        for (int s = 0; s < 2; ++s) {
#pragma unroll
            for (int mt = 0; mt < 2; ++mt) {
                const int row = w * 32 + mt * 16 + r;
                af[mt][s] = *(const bf16x8*)&Lds[buf][row * 128 +
                    ((s * 64 + 16 * g) ^ (16 * (row & 7)))];
            }
#pragma unroll
            for (int nt = 0; nt < 8; ++nt) {
                const int row = nt * 16 + r;
                bfr[nt][s] = *(const bf16x8*)&Lds[buf][16384 + row * 128 +
                    ((s * 64 + 16 * g) ^ (16 * (row & 7)))];
            }
        }
#pragma unroll
        for (int s = 0; s < 2; ++s)
#pragma unroll
            for (int mt = 0; mt < 2; ++mt)
#pragma unroll
                for (int nt = 0; nt < 8; ++nt)
                    acc[mt][nt] = __builtin_amdgcn_mfma_f32_16x16x32_bf16(
                        af[mt][s], bfr[nt][s], acc[mt][nt], 0, 0, 0);
        __syncthreads();
    }
#undef STAGE

#pragma unroll
    for (int mt = 0; mt < 2; ++mt)
#pragma unroll
        for (int nt = 0; nt < 8; ++nt) {
            const int n = n0 + nt * 16 + r;
            float bv = 0.f;
            if (EPI == E_BIASBF || EPI == E_SIGBF || EPI == E_BIASRES) bv = bias[n];
#pragma unroll
            for (int q = 0; q < 4; ++q) {
                const int m = m0 + w * 32 + mt * 16 + g * 4 + q;
                const size_t idx = (size_t)m * N + n;
                float v = acc[mt][nt][q] + bv;
                if (EPI == E_SIGBF) v = 1.f / (1.f + expf(-v));
                if (EPI == E_ACC) v += ((const float*)Cg)[idx];
                if (EPI == E_BIASRES) v += res[idx];
                if (EPI == E_BIASBF || EPI == E_SIGBF || EPI == E_CVTBF)
                    ((unsigned short*)Cg)[idx] = f2bf(v);
                else
                    ((float*)Cg)[idx] = v;
            }
        }
}

// ---------------- batch-parallel MFMA scan: 8 blocks, one batch each -------
// Block b: recurrence for batch b. 4 waves; wave w holds A^T slice for
// output states [w*64,w*64+64) in regs (af[4][8], 128 VGPR). Per step:
// Y^T = A^T @ h (M=256, K=256, N=16 all-identical columns): B-frag is a
// wave-uniform broadcast read of the 512-B h vector (free). All lanes get
// identical D columns; lane r takes component q=r&3, adds u, tanh (4
// trans-pairs/wave), lanes r<4 write bf16 h to the 16-deep LDS ring.
// u2 staged per 8-step chunk via global_load_lds (2-deep, counted
// vmcnt(2) once per chunk). h dumped per chunk: coalesced ds_read_b128 +
// fire-and-forget global_store. Zero vmem in the 8-step serial path.
__global__ __launch_bounds__(256, 1) void scan_mfma(
    const float* __restrict__ Amat, const unsigned short* __restrict__ u2bf,
    unsigned short* __restrict__ hbf)
{
    constexpr int T = 2048;
    constexpr int NCH = T / 8;  // 256 chunks
    __shared__ __align__(16) unsigned char LDSM[8192 + 2 * 4096];
    unsigned char* Hb = LDSM;            // ring [16][512]
    unsigned char* Ub = LDSM + 8192;     // [2][8 steps][512]

    const int tid = threadIdx.x;
    const int bb = blockIdx.x;           // batch 0..7
    const int w = tid >> 6, l = tid & 63;
    const int r = l & 15, g = l >> 4;
    const int m0 = w * 64;
    const bool c1 = (r & 1) != 0, c2 = (r & 2) != 0;

    if (tid < 128) ((unsigned*)Hb)[tid] = 0u;  // ring slot 0 = h_{-1} = 0

    // A^T frags: af[mt][kt](lane r,g) = Amat[kt*32+g*8+j][m0+mt*16+r]
    bf16x8 af[4][8];
#pragma unroll
    for (int mt = 0; mt < 4; ++mt) {
        const int m = m0 + mt * 16 + r;
#pragma unroll
        for (int kt = 0; kt < 8; ++kt) {
            unsigned wd[4];
#pragma unroll
            for (int jw = 0; jw < 4; ++jw) {
                const int k = kt * 32 + g * 8 + jw * 2;
                wd[jw] = pack2(Amat[(size_t)k * 256 + m],
                               Amat[(size_t)(k + 1) * 256 + m]);
            }
            af[mt][kt] = __builtin_bit_cast(bf16x8, *(uint4*)wd);
        }
    }

    const unsigned char* u2b = (const unsigned char*)u2bf + (size_t)bb * T * 512;
    unsigned short* hb = hbf + (size_t)bb * T * 256;

    // prologue: stage chunks 0 and 1
    __builtin_amdgcn_global_load_lds(
        (const __attribute__((address_space(1))) unsigned*)(u2b + tid * 16),
        (__attribute__((address_space(3))) unsigned*)(Ub + tid * 16), 16, 0, 0);
    __builtin_amdgcn_global_load_lds(
        (const __attribute__((address_space(1))) unsigned*)(u2b + 4096 + tid * 16),
        (__attribute__((address_space(3))) unsigned*)(Ub + 4096 + tid * 16), 16, 0, 0);
    asm volatile("s_waitcnt vmcnt(0) lgkmcnt(0)" ::: "memory");
    __builtin_amdgcn_sched_barrier(0);
    __builtin_amdgcn_s_barrier();
    __builtin_amdgcn_sched_barrier(0);

#define SCAN_STEP(I)                                                          \
  {                                                                           \
    bf16x8 hf[8];                                                             \
    _Pragma("unroll")                                                         \
    for (int kt = 0; kt < 8; ++kt)                                            \
      hf[kt] = *(const bf16x8*)(Hb + c15 + (I) * 512u +                       \
                                (unsigned)(kt * 64 + g * 16));                \
    float uu[4];                                                              \
    _Pragma("unroll")                                                         \
    for (int mt = 0; mt < 4; ++mt) {                                          \
      unsigned short us = *(const unsigned short*)(                           \
          Uc + (I) * 512u + (unsigned)((m0 + mt * 16 + g * 4 + (r & 3)) * 2));\
      uu[mt] = bflo(us);                                                      \
    }                                                                         \
    asm volatile("s_waitcnt lgkmcnt(0)" ::: "memory");                        \
    __builtin_amdgcn_sched_barrier(0);                                        \
    f32x4 p0[4], p1[4];                                                       \
    _Pragma("unroll")                                                         \
    for (int mt = 0; mt < 4; ++mt) {                                          \
      p0[mt] = (f32x4){0.f, 0.f, 0.f, 0.f};                                   \
      p1[mt] = (f32x4){0.f, 0.f, 0.f, 0.f};                                   \
    }                                                                         \
    _Pragma("unroll")                                                         \
    for (int kt = 0; kt < 4; ++kt) {                                          \
      _Pragma("unroll")                                                       \
      for (int mt = 0; mt < 4; ++mt) {                                        \
        p0[mt] = __builtin_amdgcn_mfma_f32_16x16x32_bf16(af[mt][kt], hf[kt],  \
                                                         p0[mt], 0, 0, 0);    \
        p1[mt] = __builtin_amdgcn_mfma_f32_16x16x32_bf16(                     \
            af[mt][kt + 4], hf[kt + 4], p1[mt], 0, 0, 0);                     \
      }                                                                       \
    }                                                                         \
    const unsigned bwb = ((I) == 7) ? (c15 ^ 4096u) : (c15 + ((I) + 1) * 512u);\
    _Pragma("unroll")                                                         \
    for (int mt = 0; mt < 4; ++mt) {                                          \
      float s0 = p0[mt][0] + p1[mt][0];                                       \
      float s1 = p0[mt][1] + p1[mt][1];                                       \
      float s2 = p0[mt][2] + p1[mt][2];                                       \
      float s3 = p0[mt][3] + p1[mt][3];                                       \
      float sv = c2 ? (c1 ? s3 : s2) : (c1 ? s1 : s0);                        \
      float hv = tanh_fast(sv + uu[mt]);                                      \
      unsigned pk;                                                            \
      asm("v_cvt_pk_bf16_f32 %0, %1, %2" : "=v"(pk) : "v"(hv), "v"(hv));      \
      if (r < 4)                                                              \
        *(unsigned short*)(Hb + bwb +                                         \
            (unsigned)((m0 + mt * 16 + g * 4 + r) * 2)) = (unsigned short)pk; \
    }                                                                         \
    asm volatile("s_waitcnt lgkmcnt(0)" ::: "memory");                        \
    __builtin_amdgcn_sched_barrier(0);                                        \
    __builtin_amdgcn_s_barrier();                                             \
    __builtin_amdgcn_sched_barrier(0);                                        \
  }

    for (int chunk = 0; chunk < NCH; ++chunk) {
        const int t0 = chunk * 8;
        const unsigned c15 = (unsigned)(t0 & 15) * 512u;
        unsigned char* Uc = Ub + ((unsigned)(chunk & 1) << 12);

        SCAN_STEP(0)
        SCAN_STEP(1)
        SCAN_STEP(2)
        SCAN_STEP(3)
        SCAN_STEP(4)
        SCAN_STEP(5)
        SCAN_STEP(6)
        SCAN_STEP(7)

        // dump this chunk's h (steps t0..t0+7) — all visible after barrier
        {
            const int flat = tid * 16;
            const int i = flat >> 9, byte = flat & 511;
            const int slot = (t0 + 1 + i) & 15;
            uint4 dat = *(const uint4*)(Hb + slot * 512 + byte);
            *(uint4*)((unsigned char*)hb + (size_t)(t0 + i) * 512 + byte) = dat;
        }
        // stage chunk+2 into the U buffer this chunk just finished reading
        if (chunk + 2 < NCH) {
            __builtin_amdgcn_global_load_lds(
                (const __attribute__((address_space(1))) unsigned*)(
                    u2b + (size_t)(t0 + 16) * 512 + tid * 16),
                (__attribute__((address_space(3))) unsigned*)(
                    Ub + ((unsigned)(chunk & 1) << 12) + tid * 16), 16, 0, 0);
            asm volatile("s_waitcnt vmcnt(2)" ::: "memory");
        } else {
            asm volatile("s_waitcnt vmcnt(1)" ::: "memory");
        }
        __builtin_amdgcn_sched_barrier(0);
        __builtin_amdgcn_s_barrier();
        __builtin_amdgcn_sched_barrier(0);
    }
#undef SCAN_STEP
}

// ---------------- elementwise gate: ys = g*big + (1-g)*x (bf16 out) --------
__global__ __launch_bounds__(256) void ewise(
    const unsigned short* __restrict__ g8, const float* __restrict__ big,
    const float* __restrict__ x, unsigned short* __restrict__ ys, int n8)
{
    int i = blockIdx.x * 256 + threadIdx.x;
    if (i >= n8) return;
    uint4 gv = ((const uint4*)g8)[i];
    float4 b0 = ((const float4*)big)[i * 2], b1 = ((const float4*)big)[i * 2 + 1];
    float4 x0 = ((const float4*)x)[i * 2], x1 = ((const float4*)x)[i * 2 + 1];
    float gg[8] = {bflo(gv.x), bfhi(gv.x), bflo(gv.y), bfhi(gv.y),
                   bflo(gv.z), bfhi(gv.z), bflo(gv.w), bfhi(gv.w)};
    float bb[8] = {b0.x, b0.y, b0.z, b0.w, b1.x, b1.y, b1.z, b1.w};
    float xx[8] = {x0.x, x0.y, x0.z, x0.w, x1.x, x1.y, x1.z, x1.w};
    float yy[8];
#pragma unroll
    for (int k = 0; k < 8; ++k) yy[k] = gg[k] * bb[k] + (1.f - gg[k]) * xx[k];
    uint4 o;
    o.x = pack2(yy[0], yy[1]); o.y = pack2(yy[2], yy[3]);
    o.z = pack2(yy[4], yy[5]); o.w = pack2(yy[6], yy[7]);
    ((uint4*)ys)[i] = o;
}

extern "C" void kernel_launch(void* const* d_in, const int* in_sizes, int n_in,
                              void* d_out, int out_size, void* d_ws, size_t ws_size,
                              hipStream_t stream)
{
    const float* x      = (const float*)d_in[0];
    const float* W_in   = (const float*)d_in[1];
    const float* b_in   = (const float*)d_in[2];
    const float* W_gate = (const float*)d_in[3];
    const float* b_gate = (const float*)d_in[4];
    const float* Amat   = (const float*)d_in[5];
    const float* Bm     = (const float*)d_in[6];
    const float* Cm     = (const float*)d_in[7];
    const float* Dm     = (const float*)d_in[8];
    const float* W_out  = (const float*)d_in[9];
    const float* b_out  = (const float*)d_in[10];

    const int T = 2048, DM = 1024, DS = 256;
    const int M = 8 * T;  // 16384
    const size_t MB = 1024 * 1024;
    char* ws = (char*)d_ws;

    unsigned short* xbf  = (unsigned short*)(ws);
    unsigned short* ysbf = xbf;  // reuse after gate GEMM
    unsigned short* u    = (unsigned short*)(ws + 32 * MB);
    unsigned short* u2   = (unsigned short*)(ws + 40 * MB);  // bf16 [16384,256]
    unsigned short* h    = (unsigned short*)(ws + 56 * MB);  // bf16 [16384,256]
    unsigned short* WinT = (unsigned short*)(ws + 64 * MB);
    unsigned short* BmT  = (unsigned short*)(ws + 64 * MB + 512 * 1024);
    unsigned short* WgT  = (unsigned short*)(ws + 65 * MB);
    unsigned short* WoT  = (unsigned short*)(ws + 67 * MB);
    unsigned short* Cbf  = (unsigned short*)(ws + 69 * MB);
    unsigned short* Dbf  = (unsigned short*)(ws + 69 * MB + 512 * 1024);
    float*          big  = (float*)(ws + 70 * MB);
    unsigned short* gbf  = (unsigned short*)(ws + 134 * MB);

    // prepass converts/transposes
    cvt_bf<<<M * DM / 8 / 256, 256, 0, stream>>>(x, xbf, M * DM / 8);
    transpose_bf<<<dim3(DS / 32, DM / 32), 256, 0, stream>>>(W_in, WinT, DM, DS);
    transpose_bf<<<dim3(DS / 32, DS / 32), 256, 0, stream>>>(Bm, BmT, DS, DS);
    transpose_bf<<<dim3(DM / 32, DM / 32), 256, 0, stream>>>(W_gate, WgT, DM, DM);
    transpose_bf<<<dim3(DM / 32, DM / 32), 256, 0, stream>>>(W_out, WoT, DM, DM);
    cvt_bf<<<DM * DS / 8 / 256, 256, 0, stream>>>(Cm, Cbf, DM * DS / 8);
    cvt_bf<<<DM * DS / 8 / 256, 256, 0, stream>>>(Dm, Dbf, DM * DS / 8);

    // u = bf16(x @ W_in + b_in)
    gemm_mfma<E_BIASBF><<<dim3(DS / 128, M / 128), 256, 0, stream>>>(
        xbf, WinT, b_in, nullptr, u, M, DS, DM);
    // big = u @ D^T
    gemm_mfma<E_NONE><<<dim3(DM / 128, M / 128), 256, 0, stream>>>(
        u, Dbf, nullptr, nullptr, big, M, DM, DS);
    // u2 = bf16(u @ Bm)
    gemm_mfma<E_CVTBF><<<dim3(DS / 128, M / 128), 256, 0, stream>>>(
        u, BmT, nullptr, nullptr, u2, M, DS, DS);
    // g = bf16(sigmoid(x @ W_gate + b_gate))
    gemm_mfma<E_SIGBF><<<dim3(DM / 128, M / 128), 256, 0, stream>>>(
        xbf, WgT, b_gate, nullptr, gbf, M, DM, DM);
    // h recurrence: one block per batch on 8 CUs
    scan_mfma<<<8, 256, 0, stream>>>(Amat, u2, h);
    // big += h @ C^T
    gemm_mfma<E_ACC><<<dim3(DM / 128, M / 128), 256, 0, stream>>>(
        h, Cbf, nullptr, nullptr, big, M, DM, DS);
    // ys = bf16(g*big + (1-g)*x)
    ewise<<<M * DM / 8 / 256, 256, 0, stream>>>(gbf, big, x, ysbf, M * DM / 8);
    // out = ys @ W_out + b_out + x
    gemm_mfma<E_BIASRES><<<dim3(DM / 128, M / 128), 256, 0, stream>>>(
        ysbf, WoT, b_out, x, (float*)d_out, M, DM, DM);
}